// Round 5
// baseline (895.612 us; speedup 1.0000x reference)
//
#include <hip/hip_runtime.h>
#include <hip/hip_bf16.h>

#define SEQ 2305
#define NROWS 4610      // B*SEQ
#define MPAD 4736       // NROWS rounded up to 128
#define DIM 512
#define QKVN 1536
#define NBS 66          // LDS stride (bf16 elems) for nearby K rows

typedef __attribute__((ext_vector_type(8))) short v8s;
typedef __attribute__((ext_vector_type(4))) float v4f;

__device__ __forceinline__ float wave_max(float x) {
    for (int o = 32; o; o >>= 1) x = fmaxf(x, __shfl_xor(x, o));
    return x;
}
__device__ __forceinline__ float wave_sum(float x) {
    for (int o = 32; o; o >>= 1) x += __shfl_xor(x, o);
    return x;
}

__device__ __forceinline__ void load_lds16(const void* g, void* l) {
    __builtin_amdgcn_global_load_lds(
        (const __attribute__((address_space(1))) void*)g,
        (__attribute__((address_space(3))) void*)l, 16, 0, 0);
}

// ---------------- copy + bf16 cast ----------------
__global__ void copy_cast(const float4* __restrict__ in, float4* __restrict__ out,
                          __hip_bfloat16* __restrict__ outb, int n4) {
    int i = blockIdx.x * blockDim.x + threadIdx.x;
    if (i >= n4) return;
    float4 v = in[i];
    out[i] = v;
    int j = i * 4;
    outb[j + 0] = __float2bfloat16(v.x);
    outb[j + 1] = __float2bfloat16(v.y);
    outb[j + 2] = __float2bfloat16(v.z);
    outb[j + 3] = __float2bfloat16(v.w);
}

// ---------------- weight transpose + bf16 convert ----------------
struct WPack { const float* p[12]; };

__global__ void transpose_weights(WPack wp, __hip_bfloat16* __restrict__ wqkv,
                                  __hip_bfloat16* __restrict__ wo) {
    __shared__ float tile[32][33];
    int m = blockIdx.z;
    const float* src = wp.p[m];
    int l = m >> 2, j = m & 3;
    __hip_bfloat16* dst = (j < 3) ? (wqkv + (size_t)l * QKVN * DIM + (size_t)j * DIM * DIM)
                                  : (wo + (size_t)l * DIM * DIM);
    int bx = blockIdx.x * 32, by = blockIdx.y * 32;
    int tx = threadIdx.x, ty = threadIdx.y;
    #pragma unroll
    for (int i = 0; i < 4; i++)
        tile[ty + 8 * i][tx] = src[(size_t)(by + ty + 8 * i) * DIM + bx + tx];
    __syncthreads();
    #pragma unroll
    for (int i = 0; i < 4; i++)
        dst[(size_t)(bx + ty + 8 * i) * DIM + by + tx] = __float2bfloat16(tile[tx][ty + 8 * i]);
}

// ---------------- m97-style LDS-staged bf16 GEMM ----------------
__global__ __launch_bounds__(256) void gemm_lds(
    const __hip_bfloat16* __restrict__ A, const __hip_bfloat16* __restrict__ Bt,
    float* __restrict__ C, const float* __restrict__ bias, const float* __restrict__ res,
    __hip_bfloat16* __restrict__ Cb, int M, int N) {
    __shared__ short As[128 * 32];   // 8 KB, row-major [128][32]
    __shared__ short Bs[128 * 32];
    const int K = 512;
    int tid = threadIdx.x;
    int wid = tid >> 6, lane = tid & 63;
    int quad = lane >> 4, l16 = lane & 15;
    int bM = blockIdx.x * 128, bN = blockIdx.y * 128;
    int wM = (wid >> 1) * 64, wN = (wid & 1) * 64;

    const short* Ag = (const short*)A;
    const short* Bg = (const short*)Bt;

    int rowA = tid >> 2, cg = tid & 3;
    const short* gA0 = Ag + (size_t)(bM + rowA) * K + cg * 8;
    const short* gA1 = Ag + (size_t)(bM + 64 + rowA) * K + cg * 8;
    const short* gB0 = Bg + (size_t)(bN + rowA) * K + cg * 8;
    const short* gB1 = Bg + (size_t)(bN + 64 + rowA) * K + cg * 8;
    short* lA0 = As + wid * 512;
    short* lA1 = As + 2048 + wid * 512;
    short* lB0 = Bs + wid * 512;
    short* lB1 = Bs + 2048 + wid * 512;

    v4f acc[4][4] = {};
    for (int k0 = 0; k0 < K; k0 += 32) {
        load_lds16(gA0 + k0, lA0);
        load_lds16(gA1 + k0, lA1);
        load_lds16(gB0 + k0, lB0);
        load_lds16(gB1 + k0, lB1);
        __syncthreads();
        v8s af[4], bf[4];
        #pragma unroll
        for (int i = 0; i < 4; i++)
            af[i] = *(const v8s*)(As + (wM + i * 16 + l16) * 32 + quad * 8);
        #pragma unroll
        for (int j = 0; j < 4; j++)
            bf[j] = *(const v8s*)(Bs + (wN + j * 16 + l16) * 32 + quad * 8);
        #pragma unroll
        for (int i = 0; i < 4; i++)
            #pragma unroll
            for (int j = 0; j < 4; j++)
                acc[i][j] = __builtin_amdgcn_mfma_f32_16x16x32_bf16(af[i], bf[j], acc[i][j], 0, 0, 0);
        __syncthreads();
    }

    #pragma unroll
    for (int i = 0; i < 4; i++) {
        int row = bM + wM + i * 16 + quad * 4;
        #pragma unroll
        for (int j = 0; j < 4; j++) {
            int col = bN + wN + j * 16 + l16;
            #pragma unroll
            for (int r = 0; r < 4; r++) {
                int rr = row + r;
                if (rr < M) {
                    float v = acc[i][j][r];
                    if (bias) v += bias[col];
                    if (res) v += res[(size_t)rr * N + col];
                    size_t idx = (size_t)rr * N + col;
                    C[idx] = v;
                    if (Cb) Cb[idx] = __float2bfloat16(v);
                }
            }
        }
    }
}

// ---------------- axial attention (typ 0/1) ----------------
__global__ __launch_bounds__(256) void axial_attn(
    const float* __restrict__ qkv, __hip_bfloat16* __restrict__ attn_b, int typ) {
    __shared__ float kl[49 * 65];
    __shared__ float vl[49 * 65];
    __shared__ float pl[4][64];
    int n = blockIdx.x;
    int b = blockIdx.y >> 3, h = blockIdx.y & 7;
    int tid = threadIdx.x;
    size_t baseQ = ((size_t)b * SEQ) * QKVN + h * 64;

    for (int idx = tid; idx < 49 * 64; idx += 256) {
        int j = idx >> 6, d = idx & 63;
        int sp = (j == 0) ? 0 : (typ == 0 ? 1 + n * 48 + (j - 1) : 1 + (j - 1) * 48 + n);
        size_t base = baseQ + (size_t)sp * QKVN + d;
        kl[j * 65 + d] = qkv[base + 512];
        vl[j * 65 + d] = qkv[base + 1024];
    }
    __syncthreads();

    int wave = tid >> 6, lane = tid & 63;
    const float NEG_INF = -__builtin_inff();
    for (int i = 1 + wave; i <= 48; i += 4) {
        int sp = typ == 0 ? 1 + n * 48 + (i - 1) : 1 + (i - 1) * 48 + n;
        const float* qrow = qkv + baseQ + (size_t)sp * QKVN;
        float dot;
        if (lane <= i) {
            float s = 0.f;
            const float* kr = &kl[lane * 65];
            #pragma unroll 8
            for (int d = 0; d < 64; d++) s += qrow[d] * kr[d];
            dot = s * 0.125f;
        } else dot = NEG_INF;
        float m = wave_max(dot);
        float e = __expf(dot - m);
        float ssum = wave_sum(e);
        pl[wave][lane] = e / ssum;
        float acc = 0.f;
        int d = lane;
        for (int j = 0; j <= i; j++) acc += pl[wave][j] * vl[j * 65 + d];
        attn_b[((size_t)b * SEQ + sp) * DIM + h * 64 + d] = __float2bfloat16(acc);
    }
    if (n == 0 && tid < 64) {
        attn_b[((size_t)b * SEQ) * DIM + h * 64 + tid] =
            __float2bfloat16(qkv[baseQ + 1024 + tid]);
    }
}

// ---------------- nearby attention: LDS-staged K, scalar-computed indices ----------------
// 2 waves/block of 128; one wave per (qp, b, h). kp is wave-uniform -> SALU.
__global__ __launch_bounds__(128) void nearby_attn(
    const float* __restrict__ qkv, __hip_bfloat16* __restrict__ attn_b) {
    __shared__ __hip_bfloat16 kl[2][100 * NBS];   // 26.4 KB
    __shared__ float ql[2][64];
    __shared__ float pl[2][128];
    int tid = threadIdx.x;
    int wave = tid >> 6, lane = tid & 63;
    int wgid = blockIdx.x * 2 + wave;
    int qp = wgid >> 4;
    int bh = wgid & 15;
    int b = bh >> 3, h = bh & 7;
    size_t base = ((size_t)b * SEQ) * QKVN + h * 64;
    size_t outIdx = ((size_t)b * SEQ + qp) * DIM + h * 64 + lane;

    if (qp == 0) {   // attends only to itself -> v[0]
        attn_b[outIdx] = __float2bfloat16(qkv[base + 1024 + lane]);
        return;
    }
    if (qp == 2304) {  // all-masked row -> uniform softmax -> mean of all V
        float a0 = 0.f, a1 = 0.f, a2 = 0.f, a3 = 0.f;
        const float* vp = qkv + base + 1024 + lane;
        int j = 0;
        for (; j + 4 <= SEQ; j += 4) {
            a0 += vp[(size_t)(j + 0) * QKVN];
            a1 += vp[(size_t)(j + 1) * QKVN];
            a2 += vp[(size_t)(j + 2) * QKVN];
            a3 += vp[(size_t)(j + 3) * QKVN];
        }
        for (; j < SEQ; j++) a0 += vp[(size_t)j * QKVN];
        attn_b[outIdx] = __float2bfloat16((a0 + a1 + a2 + a3) * (1.0f / 2305.0f));
        return;
    }

    int t = qp >> 8, r = qp & 255, hh = r >> 4, ww = r & 15;
    int t0 = t > 3 ? t - 3 : 0;
    int nc = (t - t0 + 1) * 25;

    // per-lane candidate validity for the dot phase (c = lane, c = lane+64)
    int kp1 = -1, kp2 = -1;
    {
        int c = lane;
        if (c < nc) {
            int f = c / 25, pos = c % 25;
            int tt = t0 + f, dy = pos / 5 - 2, dx = pos % 5 - 2;
            int h2 = hh + dy, w2 = ww + dx;
            if (h2 >= 0 && h2 < 16 && w2 >= 0 && w2 < 16 && (tt < t || pos < 12))
                kp1 = tt * 256 + h2 * 16 + w2 + 1;
        }
        c = lane + 64;
        if (c < nc) {
            int f = c / 25, pos = c % 25;
            int tt = t0 + f, dy = pos / 5 - 2, dx = pos % 5 - 2;
            int h2 = hh + dy, w2 = ww + dx;
            if (h2 >= 0 && h2 < 16 && w2 >= 0 && w2 < 16 && (tt < t || pos < 12))
                kp2 = tt * 256 + h2 * 16 + w2 + 1;
        }
    }
    ql[wave][lane] = qkv[base + (size_t)qp * QKVN + lane];   // coalesced

    // stage candidate K rows into LDS: kp computed in SALU (wave-uniform),
    // loads coalesced & independent -> deep vmcnt pipeline.
    const float* kb = qkv + base + 512 + lane;
    #pragma unroll 4
    for (int c = 0; c < nc; c++) {
        int f = c / 25, pos = c % 25;
        int tt = t0 + f, dy = pos / 5 - 2, dx = pos % 5 - 2;
        int h2 = hh + dy, w2 = ww + dx;
        if (h2 >= 0 && h2 < 16 && w2 >= 0 && w2 < 16 && (tt < t || pos < 12)) {
            int kp = tt * 256 + h2 * 16 + w2 + 1;
            kl[wave][c * NBS + lane] = __float2bfloat16(kb[(size_t)kp * QKVN]);
        }
    }

    // dots from LDS (lane = candidate); stride 66 -> 2-way bank alias (free)
    const float NEG = -__builtin_inff();
    float dd0 = NEG, dd1 = NEG;
    if (kp1 >= 0) {
        const unsigned* kr = (const unsigned*)&kl[wave][lane * NBS];
        float sum = 0.f;
        #pragma unroll
        for (int d2 = 0; d2 < 32; d2++) {
            unsigned u = kr[d2];
            sum += ql[wave][2 * d2] * __uint_as_float(u << 16)
                 + ql[wave][2 * d2 + 1] * __uint_as_float(u & 0xffff0000u);
        }
        dd0 = sum * 0.125f;
    }
    if (kp2 >= 0) {
        const unsigned* kr = (const unsigned*)&kl[wave][(lane + 64) * NBS];
        float sum = 0.f;
        #pragma unroll
        for (int d2 = 0; d2 < 32; d2++) {
            unsigned u = kr[d2];
            sum += ql[wave][2 * d2] * __uint_as_float(u << 16)
                 + ql[wave][2 * d2 + 1] * __uint_as_float(u & 0xffff0000u);
        }
        dd1 = sum * 0.125f;
    }

    float m = wave_max(fmaxf(dd0, dd1));
    float e0 = __expf(dd0 - m), e1 = __expf(dd1 - m);
    float inv = 1.0f / wave_sum(e0 + e1);
    pl[wave][lane] = e0 * inv;
    pl[wave][lane + 64] = e1 * inv;

    // PV: kp recomputed in SALU; coalesced, independent V loads
    const float* vb = qkv + base + 1024 + lane;
    float acc = 0.f;
    #pragma unroll 4
    for (int c = 0; c < nc; c++) {
        int f = c / 25, pos = c % 25;
        int tt = t0 + f, dy = pos / 5 - 2, dx = pos % 5 - 2;
        int h2 = hh + dy, w2 = ww + dx;
        if (h2 >= 0 && h2 < 16 && w2 >= 0 && w2 < 16 && (tt < t || pos < 12)) {
            int kp = tt * 256 + h2 * 16 + w2 + 1;
            acc += pl[wave][c] * vb[(size_t)kp * QKVN];
        }
    }
    attn_b[outIdx] = __float2bfloat16(acc);
}

// ---------------- host launch ----------------
extern "C" void kernel_launch(void* const* d_in, const int* in_sizes, int n_in,
                              void* d_out, int out_size, void* d_ws, size_t ws_size,
                              hipStream_t stream) {
    const float* x = (const float*)d_in[0];
    float* xcur = (float*)d_out;

    char* ws = (char*)d_ws;
    size_t off = 0;
    auto alloc = [&](size_t bytes) -> void* {
        void* p = ws + off;
        off = (off + bytes + 255) & ~(size_t)255;
        return p;
    };
    __hip_bfloat16* wqkv  = (__hip_bfloat16*)alloc((size_t)3 * QKVN * DIM * 2);
    __hip_bfloat16* wo    = (__hip_bfloat16*)alloc((size_t)3 * DIM * DIM * 2);
    __hip_bfloat16* xb    = (__hip_bfloat16*)alloc((size_t)MPAD * DIM * 2);
    __hip_bfloat16* attnb = (__hip_bfloat16*)alloc((size_t)MPAD * DIM * 2);
    float* qkv            = (float*)alloc((size_t)NROWS * QKVN * 4);

    const int nElem = NROWS * DIM;
    const int n4 = nElem / 4;

    copy_cast<<<(n4 + 255) / 256, 256, 0, stream>>>((const float4*)x, (float4*)xcur, xb, n4);

    WPack wp;
    for (int l = 0; l < 3; l++)
        for (int j = 0; j < 4; j++)
            wp.p[l * 4 + j] = (const float*)d_in[2 + l * 5 + j];
    transpose_weights<<<dim3(16, 16, 12), dim3(32, 8), 0, stream>>>(wp, wqkv, wo);

    for (int l = 0; l < 3; l++) {
        gemm_lds<<<dim3(MPAD / 128, QKVN / 128), 256, 0, stream>>>(
            xb, wqkv + (size_t)l * QKVN * DIM, qkv, nullptr, nullptr, nullptr, NROWS, QKVN);
        if (l < 2)
            axial_attn<<<dim3(48, 16), 256, 0, stream>>>(qkv, attnb, l);
        else
            nearby_attn<<<(SEQ * 16) / 2, 128, 0, stream>>>(qkv, attnb);
        const float* bo = (const float*)d_in[6 + l * 5];
        gemm_lds<<<dim3(MPAD / 128, DIM / 128), 256, 0, stream>>>(
            attnb, wo + (size_t)l * DIM * DIM, xcur, bo, xcur, xb, NROWS, DIM);
    }
}

// Round 6
// 562.459 us; speedup vs baseline: 1.5923x; 1.5923x over previous
//
#include <hip/hip_runtime.h>
#include <hip/hip_bf16.h>

#define SEQ 2305
#define NROWS 4610      // B*SEQ
#define MPAD 4736       // NROWS rounded up to 128
#define DIM 512
#define QKVN 1536

typedef __attribute__((ext_vector_type(8))) short v8s;
typedef __attribute__((ext_vector_type(4))) float v4f;

__device__ __forceinline__ float wave_max(float x) {
    for (int o = 32; o; o >>= 1) x = fmaxf(x, __shfl_xor(x, o));
    return x;
}
__device__ __forceinline__ float wave_sum(float x) {
    for (int o = 32; o; o >>= 1) x += __shfl_xor(x, o);
    return x;
}

__device__ __forceinline__ void load_lds16(const void* g, void* l) {
    __builtin_amdgcn_global_load_lds(
        (const __attribute__((address_space(1))) void*)g,
        (__attribute__((address_space(3))) void*)l, 16, 0, 0);
}

// ---------------- copy + bf16 cast ----------------
__global__ void copy_cast(const float4* __restrict__ in, float4* __restrict__ out,
                          __hip_bfloat16* __restrict__ outb, int n4) {
    int i = blockIdx.x * blockDim.x + threadIdx.x;
    if (i >= n4) return;
    float4 v = in[i];
    out[i] = v;
    int j = i * 4;
    outb[j + 0] = __float2bfloat16(v.x);
    outb[j + 1] = __float2bfloat16(v.y);
    outb[j + 2] = __float2bfloat16(v.z);
    outb[j + 3] = __float2bfloat16(v.w);
}

// ---------------- weight transpose + bf16 convert ----------------
struct WPack { const float* p[12]; };

__global__ void transpose_weights(WPack wp, __hip_bfloat16* __restrict__ wqkv,
                                  __hip_bfloat16* __restrict__ wo) {
    __shared__ float tile[32][33];
    int m = blockIdx.z;
    const float* src = wp.p[m];
    int l = m >> 2, j = m & 3;
    __hip_bfloat16* dst = (j < 3) ? (wqkv + (size_t)l * QKVN * DIM + (size_t)j * DIM * DIM)
                                  : (wo + (size_t)l * DIM * DIM);
    int bx = blockIdx.x * 32, by = blockIdx.y * 32;
    int tx = threadIdx.x, ty = threadIdx.y;
    #pragma unroll
    for (int i = 0; i < 4; i++)
        tile[ty + 8 * i][tx] = src[(size_t)(by + ty + 8 * i) * DIM + bx + tx];
    __syncthreads();
    #pragma unroll
    for (int i = 0; i < 4; i++)
        dst[(size_t)(bx + ty + 8 * i) * DIM + by + tx] = __float2bfloat16(tile[tx][ty + 8 * i]);
}

// ---------------- m97-style LDS-staged bf16 GEMM ----------------
__global__ __launch_bounds__(256) void gemm_lds(
    const __hip_bfloat16* __restrict__ A, const __hip_bfloat16* __restrict__ Bt,
    float* __restrict__ C, const float* __restrict__ bias, const float* __restrict__ res,
    __hip_bfloat16* __restrict__ Cb, int M, int N) {
    __shared__ short As[128 * 32];   // 8 KB, row-major [128][32]
    __shared__ short Bs[128 * 32];
    const int K = 512;
    int tid = threadIdx.x;
    int wid = tid >> 6, lane = tid & 63;
    int quad = lane >> 4, l16 = lane & 15;
    int bM = blockIdx.x * 128, bN = blockIdx.y * 128;
    int wM = (wid >> 1) * 64, wN = (wid & 1) * 64;

    const short* Ag = (const short*)A;
    const short* Bg = (const short*)Bt;

    int rowA = tid >> 2, cg = tid & 3;
    const short* gA0 = Ag + (size_t)(bM + rowA) * K + cg * 8;
    const short* gA1 = Ag + (size_t)(bM + 64 + rowA) * K + cg * 8;
    const short* gB0 = Bg + (size_t)(bN + rowA) * K + cg * 8;
    const short* gB1 = Bg + (size_t)(bN + 64 + rowA) * K + cg * 8;
    short* lA0 = As + wid * 512;
    short* lA1 = As + 2048 + wid * 512;
    short* lB0 = Bs + wid * 512;
    short* lB1 = Bs + 2048 + wid * 512;

    v4f acc[4][4] = {};
    for (int k0 = 0; k0 < K; k0 += 32) {
        load_lds16(gA0 + k0, lA0);
        load_lds16(gA1 + k0, lA1);
        load_lds16(gB0 + k0, lB0);
        load_lds16(gB1 + k0, lB1);
        __syncthreads();
        v8s af[4], bf[4];
        #pragma unroll
        for (int i = 0; i < 4; i++)
            af[i] = *(const v8s*)(As + (wM + i * 16 + l16) * 32 + quad * 8);
        #pragma unroll
        for (int j = 0; j < 4; j++)
            bf[j] = *(const v8s*)(Bs + (wN + j * 16 + l16) * 32 + quad * 8);
        #pragma unroll
        for (int i = 0; i < 4; i++)
            #pragma unroll
            for (int j = 0; j < 4; j++)
                acc[i][j] = __builtin_amdgcn_mfma_f32_16x16x32_bf16(af[i], bf[j], acc[i][j], 0, 0, 0);
        __syncthreads();
    }

    #pragma unroll
    for (int i = 0; i < 4; i++) {
        int row = bM + wM + i * 16 + quad * 4;
        #pragma unroll
        for (int j = 0; j < 4; j++) {
            int col = bN + wN + j * 16 + l16;
            #pragma unroll
            for (int r = 0; r < 4; r++) {
                int rr = row + r;
                if (rr < M) {
                    float v = acc[i][j][r];
                    if (bias) v += bias[col];
                    if (res) v += res[(size_t)rr * N + col];
                    size_t idx = (size_t)rr * N + col;
                    C[idx] = v;
                    if (Cb) Cb[idx] = __float2bfloat16(v);
                }
            }
        }
    }
}

// ---------------- axial attention (typ 0/1) ----------------
__global__ __launch_bounds__(256) void axial_attn(
    const float* __restrict__ qkv, __hip_bfloat16* __restrict__ attn_b, int typ) {
    __shared__ float kl[49 * 65];
    __shared__ float vl[49 * 65];
    __shared__ float pl[4][64];
    int n = blockIdx.x;
    int b = blockIdx.y >> 3, h = blockIdx.y & 7;
    int tid = threadIdx.x;
    size_t baseQ = ((size_t)b * SEQ) * QKVN + h * 64;

    for (int idx = tid; idx < 49 * 64; idx += 256) {
        int j = idx >> 6, d = idx & 63;
        int sp = (j == 0) ? 0 : (typ == 0 ? 1 + n * 48 + (j - 1) : 1 + (j - 1) * 48 + n);
        size_t base = baseQ + (size_t)sp * QKVN + d;
        kl[j * 65 + d] = qkv[base + 512];
        vl[j * 65 + d] = qkv[base + 1024];
    }
    __syncthreads();

    int wave = tid >> 6, lane = tid & 63;
    const float NEG_INF = -__builtin_inff();
    for (int i = 1 + wave; i <= 48; i += 4) {
        int sp = typ == 0 ? 1 + n * 48 + (i - 1) : 1 + (i - 1) * 48 + n;
        const float* qrow = qkv + baseQ + (size_t)sp * QKVN;
        float dot;
        if (lane <= i) {
            float s = 0.f;
            const float* kr = &kl[lane * 65];
            #pragma unroll 8
            for (int d = 0; d < 64; d++) s += qrow[d] * kr[d];
            dot = s * 0.125f;
        } else dot = NEG_INF;
        float m = wave_max(dot);
        float e = __expf(dot - m);
        float ssum = wave_sum(e);
        pl[wave][lane] = e / ssum;
        float acc = 0.f;
        int d = lane;
        for (int j = 0; j <= i; j++) acc += pl[wave][j] * vl[j * 65 + d];
        attn_b[((size_t)b * SEQ + sp) * DIM + h * 64 + d] = __float2bfloat16(acc);
    }
    if (n == 0 && tid < 64) {
        attn_b[((size_t)b * SEQ) * DIM + h * 64 + tid] =
            __float2bfloat16(qkv[baseQ + 1024 + tid]);
    }
}

// ---------------- mean of all V rows (for the all-masked qp=2304 row) ----------------
// stage 1: partial sums over row chunks. grid (32, 2) x 256 thr.
__global__ void meanv_part(const float* __restrict__ qkv, float* __restrict__ part) {
    int b = blockIdx.x >> 4, ch = blockIdx.x & 15;
    int col = blockIdx.y * 256 + threadIdx.x;
    int j0 = ch * 145, j1 = j0 + 145;
    if (j1 > SEQ) j1 = SEQ;
    const float* p = qkv + (size_t)b * SEQ * QKVN + 1024 + col;
    float s = 0.f;
    #pragma unroll 4
    for (int j = j0; j < j1; j++) s += p[(size_t)j * QKVN];
    part[((size_t)(b * 16 + ch)) * 512 + col] = s;
}
// stage 2: fold 16 partials. grid (2, 2) x 256 thr.
__global__ void meanv_fold(const float* __restrict__ part, float* __restrict__ meanv) {
    int b = blockIdx.x;
    int col = blockIdx.y * 256 + threadIdx.x;
    float s = 0.f;
    #pragma unroll
    for (int ch = 0; ch < 16; ch++) s += part[((size_t)(b * 16 + ch)) * 512 + col];
    meanv[b * 512 + col] = s * (1.0f / 2305.0f);
}

// ---------------- nearby attention: R1 structure + float4 gather ----------------
// 4 waves/block of 256; one wave per (qp, b, h). lane = candidate for dots.
__global__ __launch_bounds__(256) void nearby_attn(
    const float* __restrict__ qkv, const float* __restrict__ meanv,
    __hip_bfloat16* __restrict__ attn_b) {
    __shared__ float pl[4][128];
    __shared__ int kpl[4][128];
    int tid = threadIdx.x;
    int wave = tid >> 6, lane = tid & 63;
    int wgid = blockIdx.x * 4 + wave;
    int qp = wgid >> 4;
    int bh = wgid & 15;
    int b = bh >> 3, h = bh & 7;
    size_t base = ((size_t)b * SEQ) * QKVN + h * 64;
    size_t outIdx = ((size_t)b * SEQ + qp) * DIM + h * 64 + lane;

    if (qp == 0) {   // attends only to itself -> v[0]
        attn_b[outIdx] = __float2bfloat16(qkv[base + 1024 + lane]);
        return;
    }
    if (qp == 2304) {  // all-masked row -> uniform softmax -> precomputed mean of V
        attn_b[outIdx] = __float2bfloat16(meanv[b * 512 + h * 64 + lane]);
        return;
    }

    int t = qp >> 8, r = qp & 255, hh = r >> 4, ww = r & 15;
    int t0 = t > 3 ? t - 3 : 0;
    int nc = (t - t0 + 1) * 25;

    // per-lane candidates: c = lane and c = lane+64; -1 = invalid
    int kp1 = -1, kp2 = -1;
    {
        int c = lane;
        if (c < nc) {
            int f = c / 25, pos = c % 25;
            int tt = t0 + f, dy = pos / 5 - 2, dx = pos % 5 - 2;
            int h2 = hh + dy, w2 = ww + dx;
            if (h2 >= 0 && h2 < 16 && w2 >= 0 && w2 < 16 && (tt < t || pos < 12))
                kp1 = tt * 256 + h2 * 16 + w2 + 1;
        }
        c = lane + 64;
        if (c < nc) {
            int f = c / 25, pos = c % 25;
            int tt = t0 + f, dy = pos / 5 - 2, dx = pos % 5 - 2;
            int h2 = hh + dy, w2 = ww + dx;
            if (h2 >= 0 && h2 < 16 && w2 >= 0 && w2 < 16 && (tt < t || pos < 12))
                kp2 = tt * 256 + h2 * 16 + w2 + 1;
        }
    }
    kpl[wave][lane] = kp1;
    kpl[wave][lane + 64] = kp2;

    // dots: per-lane K-row gather, vectorized float4 (16B/lane/inst, all independent)
    const float4* q4  = (const float4*)(qkv + base + (size_t)qp * QKVN);
    const float4* k14 = (const float4*)(qkv + base + (size_t)(kp1 < 0 ? 0 : kp1) * QKVN + 512);
    const float4* k24 = (const float4*)(qkv + base + (size_t)(kp2 < 0 ? 0 : kp2) * QKVN + 512);
    float s0 = 0.f, s1 = 0.f;
    #pragma unroll
    for (int d4 = 0; d4 < 16; d4++) {
        float4 a = q4[d4];
        float4 x = k14[d4];
        float4 y = k24[d4];
        s0 += a.x * x.x + a.y * x.y + a.z * x.z + a.w * x.w;
        s1 += a.x * y.x + a.y * y.y + a.z * y.z + a.w * y.w;
    }
    const float NEG = -__builtin_inff();
    float dd0 = kp1 >= 0 ? s0 * 0.125f : NEG;
    float dd1 = kp2 >= 0 ? s1 * 0.125f : NEG;

    float m = wave_max(fmaxf(dd0, dd1));
    float e0 = __expf(dd0 - m), e1 = __expf(dd1 - m);
    float inv = 1.0f / wave_sum(e0 + e1);
    pl[wave][lane] = e0 * inv;
    pl[wave][lane + 64] = e1 * inv;

    // PV: coalesced V-row loads (lane = dim)
    const float* vb = qkv + base + 1024 + lane;
    float acc = 0.f;
    #pragma unroll 8
    for (int c = 0; c < nc; c++) {
        int kc = kpl[wave][c];
        if (kc >= 0) acc += pl[wave][c] * vb[(size_t)kc * QKVN];
    }
    attn_b[outIdx] = __float2bfloat16(acc);
}

// ---------------- host launch ----------------
extern "C" void kernel_launch(void* const* d_in, const int* in_sizes, int n_in,
                              void* d_out, int out_size, void* d_ws, size_t ws_size,
                              hipStream_t stream) {
    const float* x = (const float*)d_in[0];
    float* xcur = (float*)d_out;

    char* ws = (char*)d_ws;
    size_t off = 0;
    auto alloc = [&](size_t bytes) -> void* {
        void* p = ws + off;
        off = (off + bytes + 255) & ~(size_t)255;
        return p;
    };
    __hip_bfloat16* wqkv  = (__hip_bfloat16*)alloc((size_t)3 * QKVN * DIM * 2);
    __hip_bfloat16* wo    = (__hip_bfloat16*)alloc((size_t)3 * DIM * DIM * 2);
    __hip_bfloat16* xb    = (__hip_bfloat16*)alloc((size_t)MPAD * DIM * 2);
    __hip_bfloat16* attnb = (__hip_bfloat16*)alloc((size_t)MPAD * DIM * 2);
    float* part           = (float*)alloc((size_t)2 * 16 * 512 * 4);
    float* meanv          = (float*)alloc((size_t)2 * 512 * 4);
    float* qkv            = (float*)alloc((size_t)NROWS * QKVN * 4);

    const int nElem = NROWS * DIM;
    const int n4 = nElem / 4;

    copy_cast<<<(n4 + 255) / 256, 256, 0, stream>>>((const float4*)x, (float4*)xcur, xb, n4);

    WPack wp;
    for (int l = 0; l < 3; l++)
        for (int j = 0; j < 4; j++)
            wp.p[l * 4 + j] = (const float*)d_in[2 + l * 5 + j];
    transpose_weights<<<dim3(16, 16, 12), dim3(32, 8), 0, stream>>>(wp, wqkv, wo);

    for (int l = 0; l < 3; l++) {
        gemm_lds<<<dim3(MPAD / 128, QKVN / 128), 256, 0, stream>>>(
            xb, wqkv + (size_t)l * QKVN * DIM, qkv, nullptr, nullptr, nullptr, NROWS, QKVN);
        if (l < 2) {
            axial_attn<<<dim3(48, 16), 256, 0, stream>>>(qkv, attnb, l);
        } else {
            meanv_part<<<dim3(32, 2), 256, 0, stream>>>(qkv, part);
            meanv_fold<<<dim3(2, 2), 256, 0, stream>>>(part, meanv);
            nearby_attn<<<(SEQ * 16) / 4, 256, 0, stream>>>(qkv, meanv, attnb);
        }
        const float* bo = (const float*)d_in[6 + l * 5];
        gemm_lds<<<dim3(MPAD / 128, DIM / 128), 256, 0, stream>>>(
            attnb, wo + (size_t)l * DIM * DIM, xcur, bo, xcur, xb, NROWS, DIM);
    }
}

// Round 7
// 496.700 us; speedup vs baseline: 1.8031x; 1.1324x over previous
//
#include <hip/hip_runtime.h>
#include <hip/hip_bf16.h>

#define SEQ 2305
#define NROWS 4610      // B*SEQ
#define MPAD 4736       // NROWS rounded up to 128
#define DIM 512
#define QKVN 1536

typedef __attribute__((ext_vector_type(8))) short v8s;
typedef __attribute__((ext_vector_type(4))) float v4f;

__device__ __forceinline__ float bf2f(unsigned short u) {
    return __uint_as_float(((unsigned)u) << 16);
}

__device__ __forceinline__ float wave_max(float x) {
    for (int o = 32; o; o >>= 1) x = fmaxf(x, __shfl_xor(x, o));
    return x;
}
__device__ __forceinline__ float wave_sum(float x) {
    for (int o = 32; o; o >>= 1) x += __shfl_xor(x, o);
    return x;
}

__device__ __forceinline__ void load_lds16(const void* g, void* l) {
    __builtin_amdgcn_global_load_lds(
        (const __attribute__((address_space(1))) void*)g,
        (__attribute__((address_space(3))) void*)l, 16, 0, 0);
}

// ---------------- copy + bf16 cast ----------------
__global__ void copy_cast(const float4* __restrict__ in, float4* __restrict__ out,
                          __hip_bfloat16* __restrict__ outb, int n4) {
    int i = blockIdx.x * blockDim.x + threadIdx.x;
    if (i >= n4) return;
    float4 v = in[i];
    out[i] = v;
    int j = i * 4;
    outb[j + 0] = __float2bfloat16(v.x);
    outb[j + 1] = __float2bfloat16(v.y);
    outb[j + 2] = __float2bfloat16(v.z);
    outb[j + 3] = __float2bfloat16(v.w);
}

// ---------------- weight transpose + bf16 convert ----------------
struct WPack { const float* p[12]; };

__global__ void transpose_weights(WPack wp, __hip_bfloat16* __restrict__ wqkv,
                                  __hip_bfloat16* __restrict__ wo) {
    __shared__ float tile[32][33];
    int m = blockIdx.z;
    const float* src = wp.p[m];
    int l = m >> 2, j = m & 3;
    __hip_bfloat16* dst = (j < 3) ? (wqkv + (size_t)l * QKVN * DIM + (size_t)j * DIM * DIM)
                                  : (wo + (size_t)l * DIM * DIM);
    int bx = blockIdx.x * 32, by = blockIdx.y * 32;
    int tx = threadIdx.x, ty = threadIdx.y;
    #pragma unroll
    for (int i = 0; i < 4; i++)
        tile[ty + 8 * i][tx] = src[(size_t)(by + ty + 8 * i) * DIM + bx + tx];
    __syncthreads();
    #pragma unroll
    for (int i = 0; i < 4; i++)
        dst[(size_t)(bx + ty + 8 * i) * DIM + by + tx] = __float2bfloat16(tile[tx][ty + 8 * i]);
}

// ---------------- m97-style LDS-staged bf16 GEMM ----------------
// C (fp32, optional) and/or Cb (bf16, optional).
__global__ __launch_bounds__(256) void gemm_lds(
    const __hip_bfloat16* __restrict__ A, const __hip_bfloat16* __restrict__ Bt,
    float* __restrict__ C, const float* __restrict__ bias, const float* __restrict__ res,
    __hip_bfloat16* __restrict__ Cb, int M, int N) {
    __shared__ short As[128 * 32];   // 8 KB, row-major [128][32]
    __shared__ short Bs[128 * 32];
    const int K = 512;
    int tid = threadIdx.x;
    int wid = tid >> 6, lane = tid & 63;
    int quad = lane >> 4, l16 = lane & 15;
    int bM = blockIdx.x * 128, bN = blockIdx.y * 128;
    int wM = (wid >> 1) * 64, wN = (wid & 1) * 64;

    const short* Ag = (const short*)A;
    const short* Bg = (const short*)Bt;

    int rowA = tid >> 2, cg = tid & 3;
    const short* gA0 = Ag + (size_t)(bM + rowA) * K + cg * 8;
    const short* gA1 = Ag + (size_t)(bM + 64 + rowA) * K + cg * 8;
    const short* gB0 = Bg + (size_t)(bN + rowA) * K + cg * 8;
    const short* gB1 = Bg + (size_t)(bN + 64 + rowA) * K + cg * 8;
    short* lA0 = As + wid * 512;
    short* lA1 = As + 2048 + wid * 512;
    short* lB0 = Bs + wid * 512;
    short* lB1 = Bs + 2048 + wid * 512;

    v4f acc[4][4] = {};
    for (int k0 = 0; k0 < K; k0 += 32) {
        load_lds16(gA0 + k0, lA0);
        load_lds16(gA1 + k0, lA1);
        load_lds16(gB0 + k0, lB0);
        load_lds16(gB1 + k0, lB1);
        __syncthreads();
        v8s af[4], bf[4];
        #pragma unroll
        for (int i = 0; i < 4; i++)
            af[i] = *(const v8s*)(As + (wM + i * 16 + l16) * 32 + quad * 8);
        #pragma unroll
        for (int j = 0; j < 4; j++)
            bf[j] = *(const v8s*)(Bs + (wN + j * 16 + l16) * 32 + quad * 8);
        #pragma unroll
        for (int i = 0; i < 4; i++)
            #pragma unroll
            for (int j = 0; j < 4; j++)
                acc[i][j] = __builtin_amdgcn_mfma_f32_16x16x32_bf16(af[i], bf[j], acc[i][j], 0, 0, 0);
        __syncthreads();
    }

    #pragma unroll
    for (int i = 0; i < 4; i++) {
        int row = bM + wM + i * 16 + quad * 4;
        #pragma unroll
        for (int j = 0; j < 4; j++) {
            int col = bN + wN + j * 16 + l16;
            #pragma unroll
            for (int r = 0; r < 4; r++) {
                int rr = row + r;
                if (rr < M) {
                    float v = acc[i][j][r];
                    if (bias) v += bias[col];
                    if (res) v += res[(size_t)rr * N + col];
                    size_t idx = (size_t)rr * N + col;
                    if (C) C[idx] = v;
                    if (Cb) Cb[idx] = __float2bfloat16(v);
                }
            }
        }
    }
}

// ---------------- axial attention (typ 0/1), bf16 qkv ----------------
__global__ __launch_bounds__(256) void axial_attn(
    const unsigned short* __restrict__ qkvb, __hip_bfloat16* __restrict__ attn_b, int typ) {
    __shared__ float kl[49 * 65];
    __shared__ float vl[49 * 65];
    __shared__ float pl[4][64];
    int n = blockIdx.x;
    int b = blockIdx.y >> 3, h = blockIdx.y & 7;
    int tid = threadIdx.x;
    size_t baseQ = ((size_t)b * SEQ) * QKVN + h * 64;

    for (int idx = tid; idx < 49 * 64; idx += 256) {
        int j = idx >> 6, d = idx & 63;
        int sp = (j == 0) ? 0 : (typ == 0 ? 1 + n * 48 + (j - 1) : 1 + (j - 1) * 48 + n);
        size_t base = baseQ + (size_t)sp * QKVN + d;
        kl[j * 65 + d] = bf2f(qkvb[base + 512]);
        vl[j * 65 + d] = bf2f(qkvb[base + 1024]);
    }
    __syncthreads();

    int wave = tid >> 6, lane = tid & 63;
    const float NEG_INF = -__builtin_inff();
    for (int i = 1 + wave; i <= 48; i += 4) {
        int sp = typ == 0 ? 1 + n * 48 + (i - 1) : 1 + (i - 1) * 48 + n;
        const unsigned short* qrow = qkvb + baseQ + (size_t)sp * QKVN;
        float dot;
        if (lane <= i) {
            float s = 0.f;
            const float* kr = &kl[lane * 65];
            #pragma unroll 8
            for (int d = 0; d < 64; d++) s += bf2f(qrow[d]) * kr[d];
            dot = s * 0.125f;
        } else dot = NEG_INF;
        float m = wave_max(dot);
        float e = __expf(dot - m);
        float ssum = wave_sum(e);
        pl[wave][lane] = e / ssum;
        float acc = 0.f;
        int d = lane;
        for (int j = 0; j <= i; j++) acc += pl[wave][j] * vl[j * 65 + d];
        attn_b[((size_t)b * SEQ + sp) * DIM + h * 64 + d] = __float2bfloat16(acc);
    }
    if (n == 0 && tid < 64) {
        attn_b[((size_t)b * SEQ) * DIM + h * 64 + tid] =
            __float2bfloat16(bf2f(qkvb[baseQ + 1024 + tid]));
    }
}

// ---------------- mean of all V rows (for the all-masked qp=2304 row) ----------------
__global__ void meanv_part(const unsigned short* __restrict__ qkvb, float* __restrict__ part) {
    int b = blockIdx.x >> 4, ch = blockIdx.x & 15;
    int col = blockIdx.y * 256 + threadIdx.x;
    int j0 = ch * 145, j1 = j0 + 145;
    if (j1 > SEQ) j1 = SEQ;
    const unsigned short* p = qkvb + (size_t)b * SEQ * QKVN + 1024 + col;
    float s = 0.f;
    #pragma unroll 4
    for (int j = j0; j < j1; j++) s += bf2f(p[(size_t)j * QKVN]);
    part[((size_t)(b * 16 + ch)) * 512 + col] = s;
}
__global__ void meanv_fold(const float* __restrict__ part, float* __restrict__ meanv) {
    int b = blockIdx.x;
    int col = blockIdx.y * 256 + threadIdx.x;
    float s = 0.f;
    #pragma unroll
    for (int ch = 0; ch < 16; ch++) s += part[((size_t)(b * 16 + ch)) * 512 + col];
    meanv[b * 512 + col] = s * (1.0f / 2305.0f);
}

// ---------------- nearby attention: bf16 gather (half the TA line-requests) ----------------
// 4 waves/block of 256; one wave per (qp, b, h). lane = candidate for dots.
__global__ __launch_bounds__(256) void nearby_attn(
    const unsigned short* __restrict__ qkvb, const float* __restrict__ meanv,
    __hip_bfloat16* __restrict__ attn_b) {
    __shared__ float pl[4][128];
    __shared__ int kpl[4][128];
    int tid = threadIdx.x;
    int wave = tid >> 6, lane = tid & 63;
    int wgid = blockIdx.x * 4 + wave;
    int qp = wgid >> 4;
    int bh = wgid & 15;
    int b = bh >> 3, h = bh & 7;
    size_t base = ((size_t)b * SEQ) * QKVN + h * 64;
    size_t outIdx = ((size_t)b * SEQ + qp) * DIM + h * 64 + lane;

    if (qp == 0) {   // attends only to itself -> v[0]
        attn_b[outIdx] = __float2bfloat16(bf2f(qkvb[base + 1024 + lane]));
        return;
    }
    if (qp == 2304) {  // all-masked row -> uniform softmax -> precomputed mean of V
        attn_b[outIdx] = __float2bfloat16(meanv[b * 512 + h * 64 + lane]);
        return;
    }

    int t = qp >> 8, r = qp & 255, hh = r >> 4, ww = r & 15;
    int t0 = t > 3 ? t - 3 : 0;
    int nc = (t - t0 + 1) * 25;

    // per-lane candidates: c = lane and c = lane+64; -1 = invalid
    int kp1 = -1, kp2 = -1;
    {
        int c = lane;
        if (c < nc) {
            int f = c / 25, pos = c % 25;
            int tt = t0 + f, dy = pos / 5 - 2, dx = pos % 5 - 2;
            int h2 = hh + dy, w2 = ww + dx;
            if (h2 >= 0 && h2 < 16 && w2 >= 0 && w2 < 16 && (tt < t || pos < 12))
                kp1 = tt * 256 + h2 * 16 + w2 + 1;
        }
        c = lane + 64;
        if (c < nc) {
            int f = c / 25, pos = c % 25;
            int tt = t0 + f, dy = pos / 5 - 2, dx = pos % 5 - 2;
            int h2 = hh + dy, w2 = ww + dx;
            if (h2 >= 0 && h2 < 16 && w2 >= 0 && w2 < 16 && (tt < t || pos < 12))
                kp2 = tt * 256 + h2 * 16 + w2 + 1;
        }
    }
    kpl[wave][lane] = kp1;
    kpl[wave][lane + 64] = kp2;

    // dots: per-lane K-row gather, 16B loads carrying 8 bf16 each (all independent)
    const uint4* q8  = (const uint4*)(qkvb + base + (size_t)qp * QKVN);
    const uint4* k18 = (const uint4*)(qkvb + base + (size_t)(kp1 < 0 ? 0 : kp1) * QKVN + 512);
    const uint4* k28 = (const uint4*)(qkvb + base + (size_t)(kp2 < 0 ? 0 : kp2) * QKVN + 512);
    float s0 = 0.f, s1 = 0.f;
    #pragma unroll
    for (int i = 0; i < 8; i++) {
        uint4 qa = q8[i];
        uint4 ka = k18[i];
        uint4 kb = k28[i];
        const unsigned* qs = (const unsigned*)&qa;
        const unsigned* as = (const unsigned*)&ka;
        const unsigned* bs = (const unsigned*)&kb;
        #pragma unroll
        for (int j = 0; j < 4; j++) {
            float qlo = __uint_as_float(qs[j] << 16);
            float qhi = __uint_as_float(qs[j] & 0xffff0000u);
            s0 += qlo * __uint_as_float(as[j] << 16) + qhi * __uint_as_float(as[j] & 0xffff0000u);
            s1 += qlo * __uint_as_float(bs[j] << 16) + qhi * __uint_as_float(bs[j] & 0xffff0000u);
        }
    }
    const float NEG = -__builtin_inff();
    float dd0 = kp1 >= 0 ? s0 * 0.125f : NEG;
    float dd1 = kp2 >= 0 ? s1 * 0.125f : NEG;

    float m = wave_max(fmaxf(dd0, dd1));
    float e0 = __expf(dd0 - m), e1 = __expf(dd1 - m);
    float inv = 1.0f / wave_sum(e0 + e1);
    pl[wave][lane] = e0 * inv;
    pl[wave][lane + 64] = e1 * inv;

    // PV: coalesced bf16 V-row loads (lane = dim, 128B/row = 2 lines)
    const unsigned short* vb = qkvb + base + 1024 + lane;
    float acc = 0.f;
    #pragma unroll 8
    for (int c = 0; c < nc; c++) {
        int kc = kpl[wave][c];
        if (kc >= 0) acc += pl[wave][c] * bf2f(vb[(size_t)kc * QKVN]);
    }
    attn_b[outIdx] = __float2bfloat16(acc);
}

// ---------------- host launch ----------------
extern "C" void kernel_launch(void* const* d_in, const int* in_sizes, int n_in,
                              void* d_out, int out_size, void* d_ws, size_t ws_size,
                              hipStream_t stream) {
    const float* x = (const float*)d_in[0];
    float* xcur = (float*)d_out;

    char* ws = (char*)d_ws;
    size_t off = 0;
    auto alloc = [&](size_t bytes) -> void* {
        void* p = ws + off;
        off = (off + bytes + 255) & ~(size_t)255;
        return p;
    };
    __hip_bfloat16* wqkv  = (__hip_bfloat16*)alloc((size_t)3 * QKVN * DIM * 2);
    __hip_bfloat16* wo    = (__hip_bfloat16*)alloc((size_t)3 * DIM * DIM * 2);
    __hip_bfloat16* xb    = (__hip_bfloat16*)alloc((size_t)MPAD * DIM * 2);
    __hip_bfloat16* attnb = (__hip_bfloat16*)alloc((size_t)MPAD * DIM * 2);
    float* part           = (float*)alloc((size_t)2 * 16 * 512 * 4);
    float* meanv          = (float*)alloc((size_t)2 * 512 * 4);
    __hip_bfloat16* qkvb  = (__hip_bfloat16*)alloc((size_t)NROWS * QKVN * 2);

    const int nElem = NROWS * DIM;
    const int n4 = nElem / 4;

    copy_cast<<<(n4 + 255) / 256, 256, 0, stream>>>((const float4*)x, (float4*)xcur, xb, n4);

    WPack wp;
    for (int l = 0; l < 3; l++)
        for (int j = 0; j < 4; j++)
            wp.p[l * 4 + j] = (const float*)d_in[2 + l * 5 + j];
    transpose_weights<<<dim3(16, 16, 12), dim3(32, 8), 0, stream>>>(wp, wqkv, wo);

    for (int l = 0; l < 3; l++) {
        gemm_lds<<<dim3(MPAD / 128, QKVN / 128), 256, 0, stream>>>(
            xb, wqkv + (size_t)l * QKVN * DIM, nullptr, nullptr, nullptr, qkvb, NROWS, QKVN);
        if (l < 2) {
            axial_attn<<<dim3(48, 16), 256, 0, stream>>>((const unsigned short*)qkvb, attnb, l);
        } else {
            meanv_part<<<dim3(32, 2), 256, 0, stream>>>((const unsigned short*)qkvb, part);
            meanv_fold<<<dim3(2, 2), 256, 0, stream>>>(part, meanv);
            nearby_attn<<<(SEQ * 16) / 4, 256, 0, stream>>>((const unsigned short*)qkvb, meanv, attnb);
        }
        const float* bo = (const float*)d_in[6 + l * 5];
        gemm_lds<<<dim3(MPAD / 128, DIM / 128), 256, 0, stream>>>(
            attnb, wo + (size_t)l * DIM * DIM, xcur, bo, xcur, xb, NROWS, DIM);
    }
}

// Round 8
// 442.528 us; speedup vs baseline: 2.0239x; 1.1224x over previous
//
#include <hip/hip_runtime.h>
#include <hip/hip_bf16.h>

#define SEQ 2305
#define NROWS 4610      // B*SEQ
#define MPAD 4736       // NROWS rounded up to 128
#define DIM 512
#define QKVN 1536

typedef __attribute__((ext_vector_type(8))) short v8s;
typedef __attribute__((ext_vector_type(4))) float v4f;

__device__ __forceinline__ float bf2f(unsigned short u) {
    return __uint_as_float(((unsigned)u) << 16);
}

__device__ __forceinline__ float wave_max(float x) {
    for (int o = 32; o; o >>= 1) x = fmaxf(x, __shfl_xor(x, o));
    return x;
}
__device__ __forceinline__ float wave_sum(float x) {
    for (int o = 32; o; o >>= 1) x += __shfl_xor(x, o);
    return x;
}

__device__ __forceinline__ void load_lds16(const void* g, void* l) {
    __builtin_amdgcn_global_load_lds(
        (const __attribute__((address_space(1))) void*)g,
        (__attribute__((address_space(3))) void*)l, 16, 0, 0);
}

// ---------------- copy + bf16 cast ----------------
__global__ void copy_cast(const float4* __restrict__ in, float4* __restrict__ out,
                          __hip_bfloat16* __restrict__ outb, int n4) {
    int i = blockIdx.x * blockDim.x + threadIdx.x;
    if (i >= n4) return;
    float4 v = in[i];
    out[i] = v;
    int j = i * 4;
    outb[j + 0] = __float2bfloat16(v.x);
    outb[j + 1] = __float2bfloat16(v.y);
    outb[j + 2] = __float2bfloat16(v.z);
    outb[j + 3] = __float2bfloat16(v.w);
}

// ---------------- weight transpose + bf16 convert ----------------
struct WPack { const float* p[12]; };

__global__ void transpose_weights(WPack wp, __hip_bfloat16* __restrict__ wqkv,
                                  __hip_bfloat16* __restrict__ wo) {
    __shared__ float tile[32][33];
    int m = blockIdx.z;
    const float* src = wp.p[m];
    int l = m >> 2, j = m & 3;
    __hip_bfloat16* dst = (j < 3) ? (wqkv + (size_t)l * QKVN * DIM + (size_t)j * DIM * DIM)
                                  : (wo + (size_t)l * DIM * DIM);
    int bx = blockIdx.x * 32, by = blockIdx.y * 32;
    int tx = threadIdx.x, ty = threadIdx.y;
    #pragma unroll
    for (int i = 0; i < 4; i++)
        tile[ty + 8 * i][tx] = src[(size_t)(by + ty + 8 * i) * DIM + bx + tx];
    __syncthreads();
    #pragma unroll
    for (int i = 0; i < 4; i++)
        dst[(size_t)(bx + ty + 8 * i) * DIM + by + tx] = __float2bfloat16(tile[tx][ty + 8 * i]);
}

// ---------------- LDS-staged bf16 GEMM, 64x128 tile (better CU coverage) ----------------
// 256 thr = 4 waves in 2x2 (wave = 32 rows x 64 cols = 2x4 mfma 16x16x32).
__global__ __launch_bounds__(256) void gemm_lds(
    const __hip_bfloat16* __restrict__ A, const __hip_bfloat16* __restrict__ Bt,
    float* __restrict__ C, const float* __restrict__ bias, const float* __restrict__ res,
    __hip_bfloat16* __restrict__ Cb, int M, int N) {
    __shared__ short As[64 * 32];    // 4 KB
    __shared__ short Bs[128 * 32];   // 8 KB
    const int K = 512;
    int tid = threadIdx.x;
    int wid = tid >> 6, lane = tid & 63;
    int quad = lane >> 4, l16 = lane & 15;
    int bM = blockIdx.x * 64, bN = blockIdx.y * 128;
    int wM = (wid >> 1) * 32, wN = (wid & 1) * 64;

    const short* Ag = (const short*)A;
    const short* Bg = (const short*)Bt;

    int rowS = tid >> 2, cg = tid & 3;   // 4 threads per row, 8 shorts each
    const short* gA0 = Ag + (size_t)(bM + rowS) * K + cg * 8;
    const short* gB0 = Bg + (size_t)(bN + rowS) * K + cg * 8;
    const short* gB1 = Bg + (size_t)(bN + 64 + rowS) * K + cg * 8;
    short* lA0 = As + wid * 512;
    short* lB0 = Bs + wid * 512;
    short* lB1 = Bs + 2048 + wid * 512;

    v4f acc[2][4] = {};
    for (int k0 = 0; k0 < K; k0 += 32) {
        load_lds16(gA0 + k0, lA0);
        load_lds16(gB0 + k0, lB0);
        load_lds16(gB1 + k0, lB1);
        __syncthreads();
        v8s af[2], bf[4];
        #pragma unroll
        for (int i = 0; i < 2; i++)
            af[i] = *(const v8s*)(As + (wM + i * 16 + l16) * 32 + quad * 8);
        #pragma unroll
        for (int j = 0; j < 4; j++)
            bf[j] = *(const v8s*)(Bs + (wN + j * 16 + l16) * 32 + quad * 8);
        #pragma unroll
        for (int i = 0; i < 2; i++)
            #pragma unroll
            for (int j = 0; j < 4; j++)
                acc[i][j] = __builtin_amdgcn_mfma_f32_16x16x32_bf16(af[i], bf[j], acc[i][j], 0, 0, 0);
        __syncthreads();
    }

    #pragma unroll
    for (int i = 0; i < 2; i++) {
        int row = bM + wM + i * 16 + quad * 4;
        #pragma unroll
        for (int j = 0; j < 4; j++) {
            int col = bN + wN + j * 16 + l16;
            #pragma unroll
            for (int r = 0; r < 4; r++) {
                int rr = row + r;
                if (rr < M) {
                    float v = acc[i][j][r];
                    if (bias) v += bias[col];
                    if (res) v += res[(size_t)rr * N + col];
                    size_t idx = (size_t)rr * N + col;
                    if (C) C[idx] = v;
                    if (Cb) Cb[idx] = __float2bfloat16(v);
                }
            }
        }
    }
}

// ---------------- axial attention (typ 0/1), bf16 qkv ----------------
__global__ __launch_bounds__(256) void axial_attn(
    const unsigned short* __restrict__ qkvb, __hip_bfloat16* __restrict__ attn_b, int typ) {
    __shared__ float kl[49 * 65];
    __shared__ float vl[49 * 65];
    __shared__ float pl[4][64];
    int n = blockIdx.x;
    int b = blockIdx.y >> 3, h = blockIdx.y & 7;
    int tid = threadIdx.x;
    size_t baseQ = ((size_t)b * SEQ) * QKVN + h * 64;

    for (int idx = tid; idx < 49 * 64; idx += 256) {
        int j = idx >> 6, d = idx & 63;
        int sp = (j == 0) ? 0 : (typ == 0 ? 1 + n * 48 + (j - 1) : 1 + (j - 1) * 48 + n);
        size_t base = baseQ + (size_t)sp * QKVN + d;
        kl[j * 65 + d] = bf2f(qkvb[base + 512]);
        vl[j * 65 + d] = bf2f(qkvb[base + 1024]);
    }
    __syncthreads();

    int wave = tid >> 6, lane = tid & 63;
    const float NEG_INF = -__builtin_inff();
    for (int i = 1 + wave; i <= 48; i += 4) {
        int sp = typ == 0 ? 1 + n * 48 + (i - 1) : 1 + (i - 1) * 48 + n;
        const unsigned short* qrow = qkvb + baseQ + (size_t)sp * QKVN;
        float dot;
        if (lane <= i) {
            float s = 0.f;
            const float* kr = &kl[lane * 65];
            #pragma unroll 8
            for (int d = 0; d < 64; d++) s += bf2f(qrow[d]) * kr[d];
            dot = s * 0.125f;
        } else dot = NEG_INF;
        float m = wave_max(dot);
        float e = __expf(dot - m);
        float ssum = wave_sum(e);
        pl[wave][lane] = e / ssum;
        float acc = 0.f;
        int d = lane;
        for (int j = 0; j <= i; j++) acc += pl[wave][j] * vl[j * 65 + d];
        attn_b[((size_t)b * SEQ + sp) * DIM + h * 64 + d] = __float2bfloat16(acc);
    }
    if (n == 0 && tid < 64) {
        attn_b[((size_t)b * SEQ) * DIM + h * 64 + tid] =
            __float2bfloat16(bf2f(qkvb[baseQ + 1024 + tid]));
    }
}

// ---------------- mean of all V rows (for the all-masked qp=2304 row) ----------------
__global__ void meanv_part(const unsigned short* __restrict__ qkvb, float* __restrict__ part) {
    int b = blockIdx.x >> 4, ch = blockIdx.x & 15;
    int col = blockIdx.y * 256 + threadIdx.x;
    int j0 = ch * 145, j1 = j0 + 145;
    if (j1 > SEQ) j1 = SEQ;
    const unsigned short* p = qkvb + (size_t)b * SEQ * QKVN + 1024 + col;
    float s = 0.f;
    #pragma unroll 4
    for (int j = j0; j < j1; j++) s += bf2f(p[(size_t)j * QKVN]);
    part[((size_t)(b * 16 + ch)) * 512 + col] = s;
}
__global__ void meanv_fold(const float* __restrict__ part, float* __restrict__ meanv) {
    int b = blockIdx.x;
    int col = blockIdx.y * 256 + threadIdx.x;
    float s = 0.f;
    #pragma unroll
    for (int ch = 0; ch < 16; ch++) s += part[((size_t)(b * 16 + ch)) * 512 + col];
    meanv[b * 512 + col] = s * (1.0f / 2305.0f);
}

// ---------------- nearby attention: bf16 gather ----------------
// 4 waves/block of 256; one wave per (qp, b, h). lane = candidate for dots.
__global__ __launch_bounds__(256) void nearby_attn(
    const unsigned short* __restrict__ qkvb, const float* __restrict__ meanv,
    __hip_bfloat16* __restrict__ attn_b) {
    __shared__ float pl[4][128];
    __shared__ int kpl[4][128];
    int tid = threadIdx.x;
    int wave = tid >> 6, lane = tid & 63;
    int wgid = blockIdx.x * 4 + wave;
    int qp = wgid >> 4;
    int bh = wgid & 15;
    int b = bh >> 3, h = bh & 7;
    size_t base = ((size_t)b * SEQ) * QKVN + h * 64;
    size_t outIdx = ((size_t)b * SEQ + qp) * DIM + h * 64 + lane;

    if (qp == 0) {   // attends only to itself -> v[0]
        attn_b[outIdx] = __float2bfloat16(bf2f(qkvb[base + 1024 + lane]));
        return;
    }
    if (qp == 2304) {  // all-masked row -> uniform softmax -> precomputed mean of V
        attn_b[outIdx] = __float2bfloat16(meanv[b * 512 + h * 64 + lane]);
        return;
    }

    int t = qp >> 8, r = qp & 255, hh = r >> 4, ww = r & 15;
    int t0 = t > 3 ? t - 3 : 0;
    int nc = (t - t0 + 1) * 25;

    // per-lane candidates: c = lane and c = lane+64; -1 = invalid
    int kp1 = -1, kp2 = -1;
    {
        int c = lane;
        if (c < nc) {
            int f = c / 25, pos = c % 25;
            int tt = t0 + f, dy = pos / 5 - 2, dx = pos % 5 - 2;
            int h2 = hh + dy, w2 = ww + dx;
            if (h2 >= 0 && h2 < 16 && w2 >= 0 && w2 < 16 && (tt < t || pos < 12))
                kp1 = tt * 256 + h2 * 16 + w2 + 1;
        }
        c = lane + 64;
        if (c < nc) {
            int f = c / 25, pos = c % 25;
            int tt = t0 + f, dy = pos / 5 - 2, dx = pos % 5 - 2;
            int h2 = hh + dy, w2 = ww + dx;
            if (h2 >= 0 && h2 < 16 && w2 >= 0 && w2 < 16 && (tt < t || pos < 12))
                kp2 = tt * 256 + h2 * 16 + w2 + 1;
        }
    }
    kpl[wave][lane] = kp1;
    kpl[wave][lane + 64] = kp2;

    // dots: per-lane K-row gather, 16B loads carrying 8 bf16 each (all independent)
    const uint4* q8  = (const uint4*)(qkvb + base + (size_t)qp * QKVN);
    const uint4* k18 = (const uint4*)(qkvb + base + (size_t)(kp1 < 0 ? 0 : kp1) * QKVN + 512);
    const uint4* k28 = (const uint4*)(qkvb + base + (size_t)(kp2 < 0 ? 0 : kp2) * QKVN + 512);
    float s0 = 0.f, s1 = 0.f;
    #pragma unroll
    for (int i = 0; i < 8; i++) {
        uint4 qa = q8[i];
        uint4 ka = k18[i];
        uint4 kb = k28[i];
        const unsigned* qs = (const unsigned*)&qa;
        const unsigned* as = (const unsigned*)&ka;
        const unsigned* bs = (const unsigned*)&kb;
        #pragma unroll
        for (int j = 0; j < 4; j++) {
            float qlo = __uint_as_float(qs[j] << 16);
            float qhi = __uint_as_float(qs[j] & 0xffff0000u);
            s0 += qlo * __uint_as_float(as[j] << 16) + qhi * __uint_as_float(as[j] & 0xffff0000u);
            s1 += qlo * __uint_as_float(bs[j] << 16) + qhi * __uint_as_float(bs[j] & 0xffff0000u);
        }
    }
    const float NEG = -__builtin_inff();
    float dd0 = kp1 >= 0 ? s0 * 0.125f : NEG;
    float dd1 = kp2 >= 0 ? s1 * 0.125f : NEG;

    float m = wave_max(fmaxf(dd0, dd1));
    float e0 = __expf(dd0 - m), e1 = __expf(dd1 - m);
    float inv = 1.0f / wave_sum(e0 + e1);
    pl[wave][lane] = e0 * inv;
    pl[wave][lane + 64] = e1 * inv;

    // PV: coalesced bf16 V-row loads (lane = dim, 128B/row = 2 lines)
    const unsigned short* vb = qkvb + base + 1024 + lane;
    float acc = 0.f;
    #pragma unroll 8
    for (int c = 0; c < nc; c++) {
        int kc = kpl[wave][c];
        if (kc >= 0) acc += pl[wave][c] * bf2f(vb[(size_t)kc * QKVN]);
    }
    attn_b[outIdx] = __float2bfloat16(acc);
}

// ---------------- host launch ----------------
extern "C" void kernel_launch(void* const* d_in, const int* in_sizes, int n_in,
                              void* d_out, int out_size, void* d_ws, size_t ws_size,
                              hipStream_t stream) {
    const float* x = (const float*)d_in[0];
    float* xcur = (float*)d_out;

    char* ws = (char*)d_ws;
    size_t off = 0;
    auto alloc = [&](size_t bytes) -> void* {
        void* p = ws + off;
        off = (off + bytes + 255) & ~(size_t)255;
        return p;
    };
    __hip_bfloat16* wqkv  = (__hip_bfloat16*)alloc((size_t)3 * QKVN * DIM * 2);
    __hip_bfloat16* wo    = (__hip_bfloat16*)alloc((size_t)3 * DIM * DIM * 2);
    __hip_bfloat16* xb    = (__hip_bfloat16*)alloc((size_t)MPAD * DIM * 2);
    __hip_bfloat16* attnb = (__hip_bfloat16*)alloc((size_t)MPAD * DIM * 2);
    float* part           = (float*)alloc((size_t)2 * 16 * 512 * 4);
    float* meanv          = (float*)alloc((size_t)2 * 512 * 4);
    __hip_bfloat16* qkvb  = (__hip_bfloat16*)alloc((size_t)NROWS * QKVN * 2);

    const int nElem = NROWS * DIM;
    const int n4 = nElem / 4;

    copy_cast<<<(n4 + 255) / 256, 256, 0, stream>>>((const float4*)x, (float4*)xcur, xb, n4);

    WPack wp;
    for (int l = 0; l < 3; l++)
        for (int j = 0; j < 4; j++)
            wp.p[l * 4 + j] = (const float*)d_in[2 + l * 5 + j];
    transpose_weights<<<dim3(16, 16, 12), dim3(32, 8), 0, stream>>>(wp, wqkv, wo);

    for (int l = 0; l < 3; l++) {
        gemm_lds<<<dim3(MPAD / 64, QKVN / 128), 256, 0, stream>>>(
            xb, wqkv + (size_t)l * QKVN * DIM, nullptr, nullptr, nullptr, qkvb, NROWS, QKVN);
        if (l < 2) {
            axial_attn<<<dim3(48, 16), 256, 0, stream>>>((const unsigned short*)qkvb, attnb, l);
        } else {
            meanv_part<<<dim3(32, 2), 256, 0, stream>>>((const unsigned short*)qkvb, part);
            meanv_fold<<<dim3(2, 2), 256, 0, stream>>>(part, meanv);
            nearby_attn<<<(SEQ * 16) / 4, 256, 0, stream>>>((const unsigned short*)qkvb, meanv, attnb);
        }
        const float* bo = (const float*)d_in[6 + l * 5];
        gemm_lds<<<dim3(MPAD / 64, DIM / 128), 256, 0, stream>>>(
            attnb, wo + (size_t)l * DIM * DIM, xcur, bo, xcur, xb, NROWS, DIM);
    }
}

// Round 9
// 348.533 us; speedup vs baseline: 2.5697x; 1.2697x over previous
//
#include <hip/hip_runtime.h>
#include <hip/hip_bf16.h>

#define SEQ 2305
#define NROWS 4610      // B*SEQ
#define MPAD 4736       // NROWS rounded up to 128
#define DIM 512
#define QKVN 1536

typedef __attribute__((ext_vector_type(8))) short v8s;
typedef __attribute__((ext_vector_type(4))) float v4f;

__device__ __forceinline__ float bf2f(unsigned short u) {
    return __uint_as_float(((unsigned)u) << 16);
}

__device__ __forceinline__ float wave_max(float x) {
    for (int o = 32; o; o >>= 1) x = fmaxf(x, __shfl_xor(x, o));
    return x;
}
__device__ __forceinline__ float wave_sum(float x) {
    for (int o = 32; o; o >>= 1) x += __shfl_xor(x, o);
    return x;
}

__device__ __forceinline__ void load_lds16(const void* g, void* l) {
    __builtin_amdgcn_global_load_lds(
        (const __attribute__((address_space(1))) void*)g,
        (__attribute__((address_space(3))) void*)l, 16, 0, 0);
}

// ---------------- copy + bf16 cast ----------------
__global__ void copy_cast(const float4* __restrict__ in, float4* __restrict__ out,
                          __hip_bfloat16* __restrict__ outb, int n4) {
    int i = blockIdx.x * blockDim.x + threadIdx.x;
    if (i >= n4) return;
    float4 v = in[i];
    out[i] = v;
    int j = i * 4;
    outb[j + 0] = __float2bfloat16(v.x);
    outb[j + 1] = __float2bfloat16(v.y);
    outb[j + 2] = __float2bfloat16(v.z);
    outb[j + 3] = __float2bfloat16(v.w);
}

// ---------------- weight transpose + bf16 convert ----------------
struct WPack { const float* p[12]; };

__global__ void transpose_weights(WPack wp, __hip_bfloat16* __restrict__ wqkv,
                                  __hip_bfloat16* __restrict__ wo) {
    __shared__ float tile[32][33];
    int m = blockIdx.z;
    const float* src = wp.p[m];
    int l = m >> 2, j = m & 3;
    __hip_bfloat16* dst = (j < 3) ? (wqkv + (size_t)l * QKVN * DIM + (size_t)j * DIM * DIM)
                                  : (wo + (size_t)l * DIM * DIM);
    int bx = blockIdx.x * 32, by = blockIdx.y * 32;
    int tx = threadIdx.x, ty = threadIdx.y;
    #pragma unroll
    for (int i = 0; i < 4; i++)
        tile[ty + 8 * i][tx] = src[(size_t)(by + ty + 8 * i) * DIM + bx + tx];
    __syncthreads();
    #pragma unroll
    for (int i = 0; i < 4; i++)
        dst[(size_t)(bx + ty + 8 * i) * DIM + by + tx] = __float2bfloat16(tile[tx][ty + 8 * i]);
}

// ---------------- LDS-staged bf16 GEMM, 64x128 tile ----------------
__global__ __launch_bounds__(256) void gemm_lds(
    const __hip_bfloat16* __restrict__ A, const __hip_bfloat16* __restrict__ Bt,
    float* __restrict__ C, const float* __restrict__ bias, const float* __restrict__ res,
    __hip_bfloat16* __restrict__ Cb, int M, int N) {
    __shared__ short As[64 * 32];    // 4 KB
    __shared__ short Bs[128 * 32];   // 8 KB
    const int K = 512;
    int tid = threadIdx.x;
    int wid = tid >> 6, lane = tid & 63;
    int quad = lane >> 4, l16 = lane & 15;
    int bM = blockIdx.x * 64, bN = blockIdx.y * 128;
    int wM = (wid >> 1) * 32, wN = (wid & 1) * 64;

    const short* Ag = (const short*)A;
    const short* Bg = (const short*)Bt;

    int rowS = tid >> 2, cg = tid & 3;
    const short* gA0 = Ag + (size_t)(bM + rowS) * K + cg * 8;
    const short* gB0 = Bg + (size_t)(bN + rowS) * K + cg * 8;
    const short* gB1 = Bg + (size_t)(bN + 64 + rowS) * K + cg * 8;
    short* lA0 = As + wid * 512;
    short* lB0 = Bs + wid * 512;
    short* lB1 = Bs + 2048 + wid * 512;

    v4f acc[2][4] = {};
    for (int k0 = 0; k0 < K; k0 += 32) {
        load_lds16(gA0 + k0, lA0);
        load_lds16(gB0 + k0, lB0);
        load_lds16(gB1 + k0, lB1);
        __syncthreads();
        v8s af[2], bf[4];
        #pragma unroll
        for (int i = 0; i < 2; i++)
            af[i] = *(const v8s*)(As + (wM + i * 16 + l16) * 32 + quad * 8);
        #pragma unroll
        for (int j = 0; j < 4; j++)
            bf[j] = *(const v8s*)(Bs + (wN + j * 16 + l16) * 32 + quad * 8);
        #pragma unroll
        for (int i = 0; i < 2; i++)
            #pragma unroll
            for (int j = 0; j < 4; j++)
                acc[i][j] = __builtin_amdgcn_mfma_f32_16x16x32_bf16(af[i], bf[j], acc[i][j], 0, 0, 0);
        __syncthreads();
    }

    #pragma unroll
    for (int i = 0; i < 2; i++) {
        int row = bM + wM + i * 16 + quad * 4;
        #pragma unroll
        for (int j = 0; j < 4; j++) {
            int col = bN + wN + j * 16 + l16;
            #pragma unroll
            for (int r = 0; r < 4; r++) {
                int rr = row + r;
                if (rr < M) {
                    float v = acc[i][j][r];
                    if (bias) v += bias[col];
                    if (res) v += res[(size_t)rr * N + col];
                    size_t idx = (size_t)rr * N + col;
                    if (C) C[idx] = v;
                    if (Cb) Cb[idx] = __float2bfloat16(v);
                }
            }
        }
    }
}

// ---------------- axial attention (typ 0/1), bf16 qkv ----------------
__global__ __launch_bounds__(256) void axial_attn(
    const unsigned short* __restrict__ qkvb, __hip_bfloat16* __restrict__ attn_b, int typ) {
    __shared__ float kl[49 * 65];
    __shared__ float vl[49 * 65];
    __shared__ float pl[4][64];
    int n = blockIdx.x;
    int b = blockIdx.y >> 3, h = blockIdx.y & 7;
    int tid = threadIdx.x;
    size_t baseQ = ((size_t)b * SEQ) * QKVN + h * 64;

    for (int idx = tid; idx < 49 * 64; idx += 256) {
        int j = idx >> 6, d = idx & 63;
        int sp = (j == 0) ? 0 : (typ == 0 ? 1 + n * 48 + (j - 1) : 1 + (j - 1) * 48 + n);
        size_t base = baseQ + (size_t)sp * QKVN + d;
        kl[j * 65 + d] = bf2f(qkvb[base + 512]);
        vl[j * 65 + d] = bf2f(qkvb[base + 1024]);
    }
    __syncthreads();

    int wave = tid >> 6, lane = tid & 63;
    const float NEG_INF = -__builtin_inff();
    for (int i = 1 + wave; i <= 48; i += 4) {
        int sp = typ == 0 ? 1 + n * 48 + (i - 1) : 1 + (i - 1) * 48 + n;
        const unsigned short* qrow = qkvb + baseQ + (size_t)sp * QKVN;
        float dot;
        if (lane <= i) {
            float s = 0.f;
            const float* kr = &kl[lane * 65];
            #pragma unroll 8
            for (int d = 0; d < 64; d++) s += bf2f(qrow[d]) * kr[d];
            dot = s * 0.125f;
        } else dot = NEG_INF;
        float m = wave_max(dot);
        float e = __expf(dot - m);
        float ssum = wave_sum(e);
        pl[wave][lane] = e / ssum;
        float acc = 0.f;
        int d = lane;
        for (int j = 0; j <= i; j++) acc += pl[wave][j] * vl[j * 65 + d];
        attn_b[((size_t)b * SEQ + sp) * DIM + h * 64 + d] = __float2bfloat16(acc);
    }
    if (n == 0 && tid < 64) {
        attn_b[((size_t)b * SEQ) * DIM + h * 64 + tid] =
            __float2bfloat16(bf2f(qkvb[baseQ + 1024 + tid]));
    }
}

// ---------------- mean of all V rows + special seq rows 0 / 2304 ----------------
__global__ void meanv_part(const unsigned short* __restrict__ qkvb, float* __restrict__ part) {
    int b = blockIdx.x >> 4, ch = blockIdx.x & 15;
    int col = blockIdx.y * 256 + threadIdx.x;
    int j0 = ch * 145, j1 = j0 + 145;
    if (j1 > SEQ) j1 = SEQ;
    const unsigned short* p = qkvb + (size_t)b * SEQ * QKVN + 1024 + col;
    float s = 0.f;
    #pragma unroll 4
    for (int j = j0; j < j1; j++) s += bf2f(p[(size_t)j * QKVN]);
    part[((size_t)(b * 16 + ch)) * 512 + col] = s;
}
__global__ void meanv_fold(const float* __restrict__ part,
                           const unsigned short* __restrict__ qkvb,
                           __hip_bfloat16* __restrict__ attn_b) {
    int b = blockIdx.x;
    int col = blockIdx.y * 256 + threadIdx.x;
    float s = 0.f;
    #pragma unroll
    for (int ch = 0; ch < 16; ch++) s += part[((size_t)(b * 16 + ch)) * 512 + col];
    // seq row 2304: all-masked -> uniform softmax -> mean of V
    attn_b[((size_t)b * SEQ + 2304) * DIM + col] = __float2bfloat16(s * (1.0f / 2305.0f));
    // seq row 0 (bos): attends only itself -> V row 0
    attn_b[((size_t)b * SEQ) * DIM + col] =
        __float2bfloat16(bf2f(qkvb[(size_t)b * SEQ * QKVN + 1024 + col]));
}

// ---------------- nearby attention: flash-style MFMA tile kernel ----------------
// One block = 16 queries (4x4 spatial tile in frame t) x one (b,h).
// Grid 2304 = 9 frames x 16 tiles x 16 (b,h). 256 thr = 4 waves.
// Union of candidate keys: 4 frames x 8x8 window = 256 slots staged in LDS.
__global__ __launch_bounds__(256) void nearby_flash(
    const unsigned short* __restrict__ qkvb, __hip_bfloat16* __restrict__ attn_b) {
    __shared__ short KV[256 * 64];          // 32 KB: K first, reused for V
    __shared__ __hip_bfloat16 Ps[16 * 264]; // 8.25 KB, P in A-frag layout
    __shared__ float redm[16 * 4];
    __shared__ float reds[16 * 4];

    int tid = threadIdx.x;
    int wid = tid >> 6, lane = tid & 63;
    int quad = lane >> 4, l16 = lane & 15;

    int idx = blockIdx.x;
    int bh = idx & 15;
    int tile = idx >> 4;                 // 0..143
    int b = bh >> 3, h = bh & 7;
    int t = tile >> 4;                   // frame 0..8
    int sxy = tile & 15;
    int hh0 = (sxy >> 2) * 4, ww0 = (sxy & 3) * 4;
    int nf = (t < 3 ? t : 3) + 1;
    int t0 = t - (nf - 1);

    size_t rowbase = (size_t)b * SEQ;
    int hoff = h * 64;

    // ---- stage K union: slot -> (f, uy, ux); chunk-XOR swizzle vs 128B stride ----
    #pragma unroll
    for (int it = 0; it < 8; it++) {
        int linear = it * 256 + tid;
        int slot = linear >> 3;
        int cd = linear & 7;                  // dest chunk
        int cs = cd ^ (slot & 7);             // source chunk
        int f = slot >> 6, uy = (slot >> 3) & 7, ux = slot & 7;
        int kh = hh0 - 2 + uy, kw = ww0 - 2 + ux;
        int kt = t0 + f;
        bool ok = (kh >= 0) && (kh < 16) && (kw >= 0) && (kw < 16) && (f < nf);
        int kp = ok ? (kt * 256 + kh * 16 + kw + 1) : 0;
        const unsigned short* src = qkvb + (rowbase + kp) * QKVN + hoff + 512 + cs * 8;
        load_lds16(src, KV + it * 2048 + wid * 512 + lane * 8);
    }

    // ---- Q fragments direct from global (A-layout: m=l16, k=quad*8+j) ----
    int qp_f = t * 256 + (hh0 + (l16 >> 2)) * 16 + (ww0 + (l16 & 3));
    const unsigned short* qptr = qkvb + (rowbase + qp_f) * QKVN + hoff + quad * 8;
    v8s qa0 = *(const v8s*)qptr;
    v8s qa1 = *(const v8s*)(qptr + 32);

    __syncthreads();   // K staged

    // ---- S = Q K^T for this wave's 4 keytiles ----
    v4f st[4];
    #pragma unroll
    for (int k = 0; k < 4; k++) {
        int slot = (wid * 4 + k) * 16 + l16;
        int s7 = slot & 7;
        v8s blo = *(const v8s*)(KV + slot * 64 + ((quad ^ s7) * 8));
        v8s bhi = *(const v8s*)(KV + slot * 64 + (((4 + quad) ^ s7) * 8));
        v4f a = {};
        a = __builtin_amdgcn_mfma_f32_16x16x32_bf16(qa0, blo, a, 0, 0, 0);
        a = __builtin_amdgcn_mfma_f32_16x16x32_bf16(qa1, bhi, a, 0, 0, 0);
        st[k] = a;
    }

    // ---- scale + geometric mask + row-max (C layout: row=quad*4+r, col=l16) ----
    const float NEG = -3.0e38f;
    float sv[4][4];
    float pm[4] = {NEG, NEG, NEG, NEG};
    #pragma unroll
    for (int k = 0; k < 4; k++) {
        int slot = (wid * 4 + k) * 16 + l16;
        int f = slot >> 6, uy = (slot >> 3) & 7, ux = slot & 7;
        int kh = hh0 - 2 + uy, kw = ww0 - 2 + ux;
        bool okb = (kh >= 0) && (kh < 16) && (kw >= 0) && (kw < 16) && (f < nf);
        int dyp2 = uy - quad;                 // query iy = quad
        bool oky = okb && (dyp2 >= 0) && (dyp2 <= 4);
        #pragma unroll
        for (int r = 0; r < 4; r++) {
            int dxp2 = ux - r;                // query ix = r
            bool ok = oky && (dxp2 >= 0) && (dxp2 <= 4);
            if (f == nf - 1) ok = ok && (dyp2 * 5 + dxp2 < 12);  // causal raster in frame t
            float v = ok ? st[k][r] * 0.125f : NEG;
            sv[k][r] = v;
            pm[r] = fmaxf(pm[r], v);
        }
    }
    #pragma unroll
    for (int r = 0; r < 4; r++)
        for (int o = 1; o < 16; o <<= 1) pm[r] = fmaxf(pm[r], __shfl_xor(pm[r], o));
    if (l16 == 0) {
        #pragma unroll
        for (int r = 0; r < 4; r++) redm[(quad * 4 + r) * 4 + wid] = pm[r];
    }
    __syncthreads();   // rowmax partials visible; all K reads done -> KV reusable

    // ---- stage V union into KV (no swizzle; PV B-frags are scalar reads) ----
    #pragma unroll
    for (int it = 0; it < 8; it++) {
        int linear = it * 256 + tid;
        int slot = linear >> 3;
        int cd = linear & 7;
        int f = slot >> 6, uy = (slot >> 3) & 7, ux = slot & 7;
        int kh = hh0 - 2 + uy, kw = ww0 - 2 + ux;
        int kt = t0 + f;
        bool ok = (kh >= 0) && (kh < 16) && (kw >= 0) && (kw < 16) && (f < nf);
        int kp = ok ? (kt * 256 + kh * 16 + kw + 1) : 0;
        const unsigned short* src = qkvb + (rowbase + kp) * QKVN + hoff + 1024 + cd * 8;
        load_lds16(src, KV + it * 2048 + wid * 512 + lane * 8);
    }

    float rm[4];
    #pragma unroll
    for (int r = 0; r < 4; r++) {
        int row = (quad * 4 + r) * 4;
        rm[r] = fmaxf(fmaxf(redm[row], redm[row + 1]), fmaxf(redm[row + 2], redm[row + 3]));
    }

    // ---- exp, P (bf16, unnormalized) to LDS, row-sum partials ----
    float ps[4] = {0.f, 0.f, 0.f, 0.f};
    #pragma unroll
    for (int k = 0; k < 4; k++) {
        int slot = (wid * 4 + k) * 16 + l16;
        #pragma unroll
        for (int r = 0; r < 4; r++) {
            float e = __expf(sv[k][r] - rm[r]);   // masked: exp(-huge)=0
            ps[r] += e;
            Ps[(quad * 4 + r) * 264 + slot] = __float2bfloat16(e);
        }
    }
    #pragma unroll
    for (int r = 0; r < 4; r++)
        for (int o = 1; o < 16; o <<= 1) ps[r] += __shfl_xor(ps[r], o);
    if (l16 == 0) {
        #pragma unroll
        for (int r = 0; r < 4; r++) reds[(quad * 4 + r) * 4 + wid] = ps[r];
    }
    __syncthreads();   // P + sum partials visible; V staging drained

    float inv[4];
    #pragma unroll
    for (int r = 0; r < 4; r++) {
        int row = (quad * 4 + r) * 4;
        float d = reds[row] + reds[row + 1] + reds[row + 2] + reds[row + 3];
        inv[r] = 1.0f / d;    // qp==0 row: garbage, skipped on write
    }

    // ---- O-tile = P . V for dims [wid*16, wid*16+16) ----
    v4f oc = {};
    #pragma unroll
    for (int kc = 0; kc < 8; kc++) {
        v8s pa = *(const v8s*)((const short*)Ps + l16 * 264 + kc * 32 + quad * 8);
        v8s bf;
        #pragma unroll
        for (int j = 0; j < 8; j++) {
            int slot = kc * 32 + quad * 8 + j;
            bf[j] = KV[slot * 64 + wid * 16 + l16];
        }
        oc = __builtin_amdgcn_mfma_f32_16x16x32_bf16(pa, bf, oc, 0, 0, 0);
    }

    // ---- write O (row = query m = quad*4+r -> qh=hh0+quad, qw=ww0+r) ----
    #pragma unroll
    for (int r = 0; r < 4; r++) {
        int qp = t * 256 + (hh0 + quad) * 16 + (ww0 + r);
        if (qp != 0) {
            attn_b[(rowbase + qp) * DIM + hoff + wid * 16 + l16] =
                __float2bfloat16(oc[r] * inv[r]);
        }
    }
}

// ---------------- host launch ----------------
extern "C" void kernel_launch(void* const* d_in, const int* in_sizes, int n_in,
                              void* d_out, int out_size, void* d_ws, size_t ws_size,
                              hipStream_t stream) {
    const float* x = (const float*)d_in[0];
    float* xcur = (float*)d_out;

    char* ws = (char*)d_ws;
    size_t off = 0;
    auto alloc = [&](size_t bytes) -> void* {
        void* p = ws + off;
        off = (off + bytes + 255) & ~(size_t)255;
        return p;
    };
    __hip_bfloat16* wqkv  = (__hip_bfloat16*)alloc((size_t)3 * QKVN * DIM * 2);
    __hip_bfloat16* wo    = (__hip_bfloat16*)alloc((size_t)3 * DIM * DIM * 2);
    __hip_bfloat16* xb    = (__hip_bfloat16*)alloc((size_t)MPAD * DIM * 2);
    __hip_bfloat16* attnb = (__hip_bfloat16*)alloc((size_t)MPAD * DIM * 2);
    float* part           = (float*)alloc((size_t)2 * 16 * 512 * 4);
    __hip_bfloat16* qkvb  = (__hip_bfloat16*)alloc((size_t)NROWS * QKVN * 2);

    const int nElem = NROWS * DIM;
    const int n4 = nElem / 4;

    copy_cast<<<(n4 + 255) / 256, 256, 0, stream>>>((const float4*)x, (float4*)xcur, xb, n4);

    WPack wp;
    for (int l = 0; l < 3; l++)
        for (int j = 0; j < 4; j++)
            wp.p[l * 4 + j] = (const float*)d_in[2 + l * 5 + j];
    transpose_weights<<<dim3(16, 16, 12), dim3(32, 8), 0, stream>>>(wp, wqkv, wo);

    for (int l = 0; l < 3; l++) {
        gemm_lds<<<dim3(MPAD / 64, QKVN / 128), 256, 0, stream>>>(
            xb, wqkv + (size_t)l * QKVN * DIM, nullptr, nullptr, nullptr, qkvb, NROWS, QKVN);
        if (l < 2) {
            axial_attn<<<dim3(48, 16), 256, 0, stream>>>((const unsigned short*)qkvb, attnb, l);
        } else {
            meanv_part<<<dim3(32, 2), 256, 0, stream>>>((const unsigned short*)qkvb, part);
            meanv_fold<<<dim3(2, 2), 256, 0, stream>>>(part, (const unsigned short*)qkvb, attnb);
            nearby_flash<<<2304, 256, 0, stream>>>((const unsigned short*)qkvb, attnb);
        }
        const float* bo = (const float*)d_in[6 + l * 5];
        gemm_lds<<<dim3(MPAD / 64, DIM / 128), 256, 0, stream>>>(
            attnb, wo + (size_t)l * DIM * DIM, xcur, bo, xcur, xb, NROWS, DIM);
    }
}

// Round 10
// 296.946 us; speedup vs baseline: 3.0161x; 1.1737x over previous
//
#include <hip/hip_runtime.h>
#include <hip/hip_bf16.h>

#define SEQ 2305
#define NROWS 4610      // B*SEQ
#define MPAD 4736       // NROWS rounded up to 128
#define DIM 512
#define QKVN 1536

typedef __attribute__((ext_vector_type(8))) short v8s;
typedef __attribute__((ext_vector_type(4))) float v4f;

__device__ __forceinline__ float bf2f(unsigned short u) {
    return __uint_as_float(((unsigned)u) << 16);
}

__device__ __forceinline__ void load_lds16(const void* g, void* l) {
    __builtin_amdgcn_global_load_lds(
        (const __attribute__((address_space(1))) void*)g,
        (__attribute__((address_space(3))) void*)l, 16, 0, 0);
}

// ---------------- copy + bf16 cast ----------------
__global__ void copy_cast(const float4* __restrict__ in, float4* __restrict__ out,
                          __hip_bfloat16* __restrict__ outb, int n4) {
    int i = blockIdx.x * blockDim.x + threadIdx.x;
    if (i >= n4) return;
    float4 v = in[i];
    out[i] = v;
    int j = i * 4;
    outb[j + 0] = __float2bfloat16(v.x);
    outb[j + 1] = __float2bfloat16(v.y);
    outb[j + 2] = __float2bfloat16(v.z);
    outb[j + 3] = __float2bfloat16(v.w);
}

// ---------------- weight transpose + bf16 convert ----------------
struct WPack { const float* p[12]; };

__global__ void transpose_weights(WPack wp, __hip_bfloat16* __restrict__ wqkv,
                                  __hip_bfloat16* __restrict__ wo) {
    __shared__ float tile[32][33];
    int m = blockIdx.z;
    const float* src = wp.p[m];
    int l = m >> 2, j = m & 3;
    __hip_bfloat16* dst = (j < 3) ? (wqkv + (size_t)l * QKVN * DIM + (size_t)j * DIM * DIM)
                                  : (wo + (size_t)l * DIM * DIM);
    int bx = blockIdx.x * 32, by = blockIdx.y * 32;
    int tx = threadIdx.x, ty = threadIdx.y;
    #pragma unroll
    for (int i = 0; i < 4; i++)
        tile[ty + 8 * i][tx] = src[(size_t)(by + ty + 8 * i) * DIM + bx + tx];
    __syncthreads();
    #pragma unroll
    for (int i = 0; i < 4; i++)
        dst[(size_t)(bx + ty + 8 * i) * DIM + by + tx] = __float2bfloat16(tile[tx][ty + 8 * i]);
}

// ---------------- LDS-staged bf16 GEMM, 64x128 tile ----------------
__global__ __launch_bounds__(256) void gemm_lds(
    const __hip_bfloat16* __restrict__ A, const __hip_bfloat16* __restrict__ Bt,
    float* __restrict__ C, const float* __restrict__ bias, const float* __restrict__ res,
    __hip_bfloat16* __restrict__ Cb, int M, int N) {
    __shared__ short As[64 * 32];    // 4 KB
    __shared__ short Bs[128 * 32];   // 8 KB
    const int K = 512;
    int tid = threadIdx.x;
    int wid = tid >> 6, lane = tid & 63;
    int quad = lane >> 4, l16 = lane & 15;
    int bM = blockIdx.x * 64, bN = blockIdx.y * 128;
    int wM = (wid >> 1) * 32, wN = (wid & 1) * 64;

    const short* Ag = (const short*)A;
    const short* Bg = (const short*)Bt;

    int rowS = tid >> 2, cg = tid & 3;
    const short* gA0 = Ag + (size_t)(bM + rowS) * K + cg * 8;
    const short* gB0 = Bg + (size_t)(bN + rowS) * K + cg * 8;
    const short* gB1 = Bg + (size_t)(bN + 64 + rowS) * K + cg * 8;
    short* lA0 = As + wid * 512;
    short* lB0 = Bs + wid * 512;
    short* lB1 = Bs + 2048 + wid * 512;

    v4f acc[2][4] = {};
    for (int k0 = 0; k0 < K; k0 += 32) {
        load_lds16(gA0 + k0, lA0);
        load_lds16(gB0 + k0, lB0);
        load_lds16(gB1 + k0, lB1);
        __syncthreads();
        v8s af[2], bf[4];
        #pragma unroll
        for (int i = 0; i < 2; i++)
            af[i] = *(const v8s*)(As + (wM + i * 16 + l16) * 32 + quad * 8);
        #pragma unroll
        for (int j = 0; j < 4; j++)
            bf[j] = *(const v8s*)(Bs + (wN + j * 16 + l16) * 32 + quad * 8);
        #pragma unroll
        for (int i = 0; i < 2; i++)
            #pragma unroll
            for (int j = 0; j < 4; j++)
                acc[i][j] = __builtin_amdgcn_mfma_f32_16x16x32_bf16(af[i], bf[j], acc[i][j], 0, 0, 0);
        __syncthreads();
    }

    #pragma unroll
    for (int i = 0; i < 2; i++) {
        int row = bM + wM + i * 16 + quad * 4;
        #pragma unroll
        for (int j = 0; j < 4; j++) {
            int col = bN + wN + j * 16 + l16;
            #pragma unroll
            for (int r = 0; r < 4; r++) {
                int rr = row + r;
                if (rr < M) {
                    float v = acc[i][j][r];
                    if (bias) v += bias[col];
                    if (res) v += res[(size_t)rr * N + col];
                    size_t idx = (size_t)rr * N + col;
                    if (C) C[idx] = v;
                    if (Cb) Cb[idx] = __float2bfloat16(v);
                }
            }
        }
    }
}

// ---------------- axial attention, flash-style MFMA ----------------
// One block per (n, b, h): 49 keys (j=0 bos + 48), 48 queries. grid (48,16), 256 thr.
__global__ __launch_bounds__(256) void axial_flash(
    const unsigned short* __restrict__ qkvb, __hip_bfloat16* __restrict__ attn_b, int typ) {
    __shared__ short Ks[64 * 64];    // 8 KB, chunk-XOR swizzled
    __shared__ short Vs[64 * 64];    // 8 KB, linear
    __shared__ short Ps[64 * 72];    // 9 KB, P bf16 (stride 72 shorts = 144 B)
    __shared__ float invl[64];

    int tid = threadIdx.x;
    int wid = tid >> 6, lane = tid & 63;
    int quad = lane >> 4, l16 = lane & 15;
    int n = blockIdx.x;
    int b = blockIdx.y >> 3, h = blockIdx.y & 7;
    size_t rowbase = (size_t)b * SEQ;
    int hoff = h * 64;

    // ---- stage K (swizzled) and V (linear): 64 rows x 8 chunks each ----
    #pragma unroll
    for (int it = 0; it < 2; it++) {
        int linear = it * 256 + tid;
        int slot = linear >> 3;          // key row j
        int cd = linear & 7;
        int cs = cd ^ (slot & 7);
        int sp = (slot == 0) ? 0
               : (slot <= 48 ? (typ == 0 ? 1 + n * 48 + (slot - 1) : 1 + (slot - 1) * 48 + n) : 0);
        const unsigned short* srcK = qkvb + (rowbase + sp) * QKVN + hoff + 512 + cs * 8;
        load_lds16(srcK, Ks + it * 2048 + wid * 512 + lane * 8);
        const unsigned short* srcV = qkvb + (rowbase + sp) * QKVN + hoff + 1024 + cd * 8;
        load_lds16(srcV, Vs + it * 2048 + wid * 512 + lane * 8);
    }

    // ---- Q fragments (A-layout: m = l16 -> query i = wid*16 + l16) ----
    int qi = wid * 16 + l16;
    int sp_q = (qi >= 1 && qi <= 48)
             ? (typ == 0 ? 1 + n * 48 + (qi - 1) : 1 + (qi - 1) * 48 + n) : 0;
    const unsigned short* qptr = qkvb + (rowbase + sp_q) * QKVN + hoff + quad * 8;
    v8s qa0 = *(const v8s*)qptr;
    v8s qa1 = *(const v8s*)(qptr + 32);

    __syncthreads();   // K,V staged

    // bos output (query 0 attends only itself -> V row 0)
    if (n == 0 && tid < 64) {
        attn_b[rowbase * DIM + hoff + tid] =
            __float2bfloat16(bf2f(qkvb[rowbase * QKVN + hoff + 1024 + tid]));
    }

    // ---- S = Q K^T: wave wid owns q-tile wid, all 4 key tiles ----
    v4f st[4];
    #pragma unroll
    for (int kt = 0; kt < 4; kt++) {
        int slot = kt * 16 + l16;
        int s7 = slot & 7;
        v8s blo = *(const v8s*)(Ks + slot * 64 + ((quad ^ s7) * 8));
        v8s bhi = *(const v8s*)(Ks + slot * 64 + (((4 + quad) ^ s7) * 8));
        v4f a = {};
        a = __builtin_amdgcn_mfma_f32_16x16x32_bf16(qa0, blo, a, 0, 0, 0);
        a = __builtin_amdgcn_mfma_f32_16x16x32_bf16(qa1, bhi, a, 0, 0, 0);
        st[kt] = a;
    }

    // ---- mask (causal, j<=i) + row softmax, fully in-wave ----
    const float NEG = -3.0e38f;
    float sv[4][4];
    float pm[4] = {NEG, NEG, NEG, NEG};
    #pragma unroll
    for (int kt = 0; kt < 4; kt++) {
        int j = kt * 16 + l16;
        #pragma unroll
        for (int r = 0; r < 4; r++) {
            int i = wid * 16 + quad * 4 + r;
            bool ok = (i >= 1) && (i <= 48) && (j <= i);
            float v = ok ? st[kt][r] * 0.125f : NEG;
            sv[kt][r] = v;
            pm[r] = fmaxf(pm[r], v);
        }
    }
    #pragma unroll
    for (int r = 0; r < 4; r++)
        for (int o = 1; o < 16; o <<= 1) pm[r] = fmaxf(pm[r], __shfl_xor(pm[r], o));

    float ps[4] = {0.f, 0.f, 0.f, 0.f};
    #pragma unroll
    for (int kt = 0; kt < 4; kt++) {
        int j = kt * 16 + l16;
        #pragma unroll
        for (int r = 0; r < 4; r++) {
            float e = __expf(sv[kt][r] - pm[r]);
            ps[r] += e;
            Ps[(wid * 16 + quad * 4 + r) * 72 + j] = (short)__bfloat16_as_ushort(__float2bfloat16(e));
        }
    }
    #pragma unroll
    for (int r = 0; r < 4; r++)
        for (int o = 1; o < 16; o <<= 1) ps[r] += __shfl_xor(ps[r], o);
    if (l16 == 0) {
        #pragma unroll
        for (int r = 0; r < 4; r++)
            invl[wid * 16 + quad * 4 + r] = 1.0f / ps[r];
    }
    __syncthreads();   // P + inv visible

    // ---- O = P V : wave wid owns dim chunk wid*16..+15, loops q-tiles ----
    #pragma unroll
    for (int qt = 0; qt < 4; qt++) {
        v4f oc = {};
        #pragma unroll
        for (int kc = 0; kc < 2; kc++) {
            v8s pa = *(const v8s*)(Ps + (qt * 16 + l16) * 72 + kc * 32 + quad * 8);
            v8s bfr;
            #pragma unroll
            for (int jj = 0; jj < 8; jj++)
                bfr[jj] = Vs[(kc * 32 + quad * 8 + jj) * 64 + wid * 16 + l16];
            oc = __builtin_amdgcn_mfma_f32_16x16x32_bf16(pa, bfr, oc, 0, 0, 0);
        }
        #pragma unroll
        for (int r = 0; r < 4; r++) {
            int i = qt * 16 + quad * 4 + r;
            if (i >= 1 && i <= 48) {
                int sp = typ == 0 ? 1 + n * 48 + (i - 1) : 1 + (i - 1) * 48 + n;
                attn_b[(rowbase + sp) * DIM + hoff + wid * 16 + l16] =
                    __float2bfloat16(oc[r] * invl[i]);
            }
        }
    }
}

// ---------------- mean of all V rows + special seq rows 0 / 2304 ----------------
__global__ void meanv_part(const unsigned short* __restrict__ qkvb, float* __restrict__ part) {
    int b = blockIdx.x >> 4, ch = blockIdx.x & 15;
    int col = blockIdx.y * 256 + threadIdx.x;
    int j0 = ch * 145, j1 = j0 + 145;
    if (j1 > SEQ) j1 = SEQ;
    const unsigned short* p = qkvb + (size_t)b * SEQ * QKVN + 1024 + col;
    float s = 0.f;
    #pragma unroll 4
    for (int j = j0; j < j1; j++) s += bf2f(p[(size_t)j * QKVN]);
    part[((size_t)(b * 16 + ch)) * 512 + col] = s;
}
__global__ void meanv_fold(const float* __restrict__ part,
                           const unsigned short* __restrict__ qkvb,
                           __hip_bfloat16* __restrict__ attn_b) {
    int b = blockIdx.x;
    int col = blockIdx.y * 256 + threadIdx.x;
    float s = 0.f;
    #pragma unroll
    for (int ch = 0; ch < 16; ch++) s += part[((size_t)(b * 16 + ch)) * 512 + col];
    attn_b[((size_t)b * SEQ + 2304) * DIM + col] = __float2bfloat16(s * (1.0f / 2305.0f));
    attn_b[((size_t)b * SEQ) * DIM + col] =
        __float2bfloat16(bf2f(qkvb[(size_t)b * SEQ * QKVN + 1024 + col]));
}

// ---------------- nearby attention: flash-style MFMA tile kernel ----------------
__global__ __launch_bounds__(256) void nearby_flash(
    const unsigned short* __restrict__ qkvb, __hip_bfloat16* __restrict__ attn_b) {
    __shared__ short KV[256 * 64];          // 32 KB: K first, reused for V
    __shared__ __hip_bfloat16 Ps[16 * 264]; // 8.25 KB, P in A-frag layout
    __shared__ float redm[16 * 4];
    __shared__ float reds[16 * 4];

    int tid = threadIdx.x;
    int wid = tid >> 6, lane = tid & 63;
    int quad = lane >> 4, l16 = lane & 15;

    int idx = blockIdx.x;
    int bh = idx & 15;
    int tile = idx >> 4;
    int b = bh >> 3, h = bh & 7;
    int t = tile >> 4;
    int sxy = tile & 15;
    int hh0 = (sxy >> 2) * 4, ww0 = (sxy & 3) * 4;
    int nf = (t < 3 ? t : 3) + 1;
    int t0 = t - (nf - 1);

    size_t rowbase = (size_t)b * SEQ;
    int hoff = h * 64;

    #pragma unroll
    for (int it = 0; it < 8; it++) {
        int linear = it * 256 + tid;
        int slot = linear >> 3;
        int cd = linear & 7;
        int cs = cd ^ (slot & 7);
        int f = slot >> 6, uy = (slot >> 3) & 7, ux = slot & 7;
        int kh = hh0 - 2 + uy, kw = ww0 - 2 + ux;
        int kt = t0 + f;
        bool ok = (kh >= 0) && (kh < 16) && (kw >= 0) && (kw < 16) && (f < nf);
        int kp = ok ? (kt * 256 + kh * 16 + kw + 1) : 0;
        const unsigned short* src = qkvb + (rowbase + kp) * QKVN + hoff + 512 + cs * 8;
        load_lds16(src, KV + it * 2048 + wid * 512 + lane * 8);
    }

    int qp_f = t * 256 + (hh0 + (l16 >> 2)) * 16 + (ww0 + (l16 & 3));
    const unsigned short* qptr = qkvb + (rowbase + qp_f) * QKVN + hoff + quad * 8;
    v8s qa0 = *(const v8s*)qptr;
    v8s qa1 = *(const v8s*)(qptr + 32);

    __syncthreads();

    v4f st[4];
    #pragma unroll
    for (int k = 0; k < 4; k++) {
        int slot = (wid * 4 + k) * 16 + l16;
        int s7 = slot & 7;
        v8s blo = *(const v8s*)(KV + slot * 64 + ((quad ^ s7) * 8));
        v8s bhi = *(const v8s*)(KV + slot * 64 + (((4 + quad) ^ s7) * 8));
        v4f a = {};
        a = __builtin_amdgcn_mfma_f32_16x16x32_bf16(qa0, blo, a, 0, 0, 0);
        a = __builtin_amdgcn_mfma_f32_16x16x32_bf16(qa1, bhi, a, 0, 0, 0);
        st[k] = a;
    }

    const float NEG = -3.0e38f;
    float sv[4][4];
    float pm[4] = {NEG, NEG, NEG, NEG};
    #pragma unroll
    for (int k = 0; k < 4; k++) {
        int slot = (wid * 4 + k) * 16 + l16;
        int f = slot >> 6, uy = (slot >> 3) & 7, ux = slot & 7;
        int kh = hh0 - 2 + uy, kw = ww0 - 2 + ux;
        bool okb = (kh >= 0) && (kh < 16) && (kw >= 0) && (kw < 16) && (f < nf);
        int dyp2 = uy - quad;
        bool oky = okb && (dyp2 >= 0) && (dyp2 <= 4);
        #pragma unroll
        for (int r = 0; r < 4; r++) {
            int dxp2 = ux - r;
            bool ok = oky && (dxp2 >= 0) && (dxp2 <= 4);
            if (f == nf - 1) ok = ok && (dyp2 * 5 + dxp2 < 12);
            float v = ok ? st[k][r] * 0.125f : NEG;
            sv[k][r] = v;
            pm[r] = fmaxf(pm[r], v);
        }
    }
    #pragma unroll
    for (int r = 0; r < 4; r++)
        for (int o = 1; o < 16; o <<= 1) pm[r] = fmaxf(pm[r], __shfl_xor(pm[r], o));
    if (l16 == 0) {
        #pragma unroll
        for (int r = 0; r < 4; r++) redm[(quad * 4 + r) * 4 + wid] = pm[r];
    }
    __syncthreads();

    #pragma unroll
    for (int it = 0; it < 8; it++) {
        int linear = it * 256 + tid;
        int slot = linear >> 3;
        int cd = linear & 7;
        int f = slot >> 6, uy = (slot >> 3) & 7, ux = slot & 7;
        int kh = hh0 - 2 + uy, kw = ww0 - 2 + ux;
        int kt = t0 + f;
        bool ok = (kh >= 0) && (kh < 16) && (kw >= 0) && (kw < 16) && (f < nf);
        int kp = ok ? (kt * 256 + kh * 16 + kw + 1) : 0;
        const unsigned short* src = qkvb + (rowbase + kp) * QKVN + hoff + 1024 + cd * 8;
        load_lds16(src, KV + it * 2048 + wid * 512 + lane * 8);
    }

    float rm[4];
    #pragma unroll
    for (int r = 0; r < 4; r++) {
        int row = (quad * 4 + r) * 4;
        rm[r] = fmaxf(fmaxf(redm[row], redm[row + 1]), fmaxf(redm[row + 2], redm[row + 3]));
    }

    float ps[4] = {0.f, 0.f, 0.f, 0.f};
    #pragma unroll
    for (int k = 0; k < 4; k++) {
        int slot = (wid * 4 + k) * 16 + l16;
        #pragma unroll
        for (int r = 0; r < 4; r++) {
            float e = __expf(sv[k][r] - rm[r]);
            ps[r] += e;
            Ps[(quad * 4 + r) * 264 + slot] = __float2bfloat16(e);
        }
    }
    #pragma unroll
    for (int r = 0; r < 4; r++)
        for (int o = 1; o < 16; o <<= 1) ps[r] += __shfl_xor(ps[r], o);
    if (l16 == 0) {
        #pragma unroll
        for (int r = 0; r < 4; r++) reds[(quad * 4 + r) * 4 + wid] = ps[r];
    }
    __syncthreads();

    float inv[4];
    #pragma unroll
    for (int r = 0; r < 4; r++) {
        int row = (quad * 4 + r) * 4;
        float d = reds[row] + reds[row + 1] + reds[row + 2] + reds[row + 3];
        inv[r] = 1.0f / d;
    }

    v4f oc = {};
    #pragma unroll
    for (int kc = 0; kc < 8; kc++) {
        v8s pa = *(const v8s*)((const short*)Ps + l16 * 264 + kc * 32 + quad * 8);
        v8s bf;
        #pragma unroll
        for (int j = 0; j < 8; j++) {
            int slot = kc * 32 + quad * 8 + j;
            bf[j] = KV[slot * 64 + wid * 16 + l16];
        }
        oc = __builtin_amdgcn_mfma_f32_16x16x32_bf16(pa, bf, oc, 0, 0, 0);
    }

    #pragma unroll
    for (int r = 0; r < 4; r++) {
        int qp = t * 256 + (hh0 + quad) * 16 + (ww0 + r);
        if (qp != 0) {
            attn_b[(rowbase + qp) * DIM + hoff + wid * 16 + l16] =
                __float2bfloat16(oc[r] * inv[r]);
        }
    }
}

// ---------------- host launch ----------------
extern "C" void kernel_launch(void* const* d_in, const int* in_sizes, int n_in,
                              void* d_out, int out_size, void* d_ws, size_t ws_size,
                              hipStream_t stream) {
    const float* x = (const float*)d_in[0];
    float* xcur = (float*)d_out;

    char* ws = (char*)d_ws;
    size_t off = 0;
    auto alloc = [&](size_t bytes) -> void* {
        void* p = ws + off;
        off = (off + bytes + 255) & ~(size_t)255;
        return p;
    };
    __hip_bfloat16* wqkv  = (__hip_bfloat16*)alloc((size_t)3 * QKVN * DIM * 2);
    __hip_bfloat16* wo    = (__hip_bfloat16*)alloc((size_t)3 * DIM * DIM * 2);
    __hip_bfloat16* xb    = (__hip_bfloat16*)alloc((size_t)MPAD * DIM * 2);
    __hip_bfloat16* attnb = (__hip_bfloat16*)alloc((size_t)MPAD * DIM * 2);
    float* part           = (float*)alloc((size_t)2 * 16 * 512 * 4);
    __hip_bfloat16* qkvb  = (__hip_bfloat16*)alloc((size_t)NROWS * QKVN * 2);

    const int nElem = NROWS * DIM;
    const int n4 = nElem / 4;

    copy_cast<<<(n4 + 255) / 256, 256, 0, stream>>>((const float4*)x, (float4*)xcur, xb, n4);

    WPack wp;
    for (int l = 0; l < 3; l++)
        for (int j = 0; j < 4; j++)
            wp.p[l * 4 + j] = (const float*)d_in[2 + l * 5 + j];
    transpose_weights<<<dim3(16, 16, 12), dim3(32, 8), 0, stream>>>(wp, wqkv, wo);

    for (int l = 0; l < 3; l++) {
        gemm_lds<<<dim3(MPAD / 64, QKVN / 128), 256, 0, stream>>>(
            xb, wqkv + (size_t)l * QKVN * DIM, nullptr, nullptr, nullptr, qkvb, NROWS, QKVN);
        if (l < 2) {
            axial_flash<<<dim3(48, 16), 256, 0, stream>>>((const unsigned short*)qkvb, attnb, l);
        } else {
            meanv_part<<<dim3(32, 2), 256, 0, stream>>>((const unsigned short*)qkvb, part);
            meanv_fold<<<dim3(2, 2), 256, 0, stream>>>(part, (const unsigned short*)qkvb, attnb);
            nearby_flash<<<2304, 256, 0, stream>>>((const unsigned short*)qkvb, attnb);
        }
        const float* bo = (const float*)d_in[6 + l * 5];
        gemm_lds<<<dim3(MPAD / 64, DIM / 128), 256, 0, stream>>>(
            attnb, wo + (size_t)l * DIM * DIM, xcur, bo, xcur, xb, NROWS, DIM);
    }
}

// Round 11
// 295.238 us; speedup vs baseline: 3.0335x; 1.0058x over previous
//
#include <hip/hip_runtime.h>
#include <hip/hip_bf16.h>

#define SEQ 2305
#define NROWS 4610      // B*SEQ
#define MPAD 4736       // NROWS rounded up to 128
#define DIM 512
#define QKVN 1536

typedef __attribute__((ext_vector_type(8))) short v8s;
typedef __attribute__((ext_vector_type(4))) float v4f;

__device__ __forceinline__ float bf2f(unsigned short u) {
    return __uint_as_float(((unsigned)u) << 16);
}

__device__ __forceinline__ void load_lds16(const void* g, void* l) {
    __builtin_amdgcn_global_load_lds(
        (const __attribute__((address_space(1))) void*)g,
        (__attribute__((address_space(3))) void*)l, 16, 0, 0);
}

// ---------------- weight transpose + bf16 convert, fused with x copy/cast ----------------
struct WPack { const float* p[12]; };

__global__ void prep_inputs(WPack wp, __hip_bfloat16* __restrict__ wqkv,
                            __hip_bfloat16* __restrict__ wo,
                            const float4* __restrict__ xin, float4* __restrict__ xout,
                            __hip_bfloat16* __restrict__ xb, int n4) {
    int tx = threadIdx.x, ty = threadIdx.y;
    int m = blockIdx.z;
    if (m == 12) {   // copy x -> xcur (fp32) + xb (bf16), grid-stride
        int tidl = ty * 32 + tx;
        int bid = blockIdx.y * 16 + blockIdx.x;
        for (int i = bid * 256 + tidl; i < n4; i += 65536) {
            float4 v = xin[i];
            xout[i] = v;
            int j = i * 4;
            xb[j + 0] = __float2bfloat16(v.x);
            xb[j + 1] = __float2bfloat16(v.y);
            xb[j + 2] = __float2bfloat16(v.z);
            xb[j + 3] = __float2bfloat16(v.w);
        }
        return;
    }
    __shared__ float tile[32][33];
    const float* src = wp.p[m];
    int l = m >> 2, j = m & 3;
    __hip_bfloat16* dst = (j < 3) ? (wqkv + (size_t)l * QKVN * DIM + (size_t)j * DIM * DIM)
                                  : (wo + (size_t)l * DIM * DIM);
    int bx = blockIdx.x * 32, by = blockIdx.y * 32;
    #pragma unroll
    for (int i = 0; i < 4; i++)
        tile[ty + 8 * i][tx] = src[(size_t)(by + ty + 8 * i) * DIM + bx + tx];
    __syncthreads();
    #pragma unroll
    for (int i = 0; i < 4; i++)
        dst[(size_t)(bx + ty + 8 * i) * DIM + by + tx] = __float2bfloat16(tile[tx][ty + 8 * i]);
}

// ---------------- LDS-staged bf16 GEMM, 64x128 tile, BK=64 (twin 32-k sub-buffers) ----------------
__global__ __launch_bounds__(256) void gemm_lds(
    const __hip_bfloat16* __restrict__ A, const __hip_bfloat16* __restrict__ Bt,
    float* __restrict__ C, const float* __restrict__ bias, const float* __restrict__ res,
    __hip_bfloat16* __restrict__ Cb, int M, int N) {
    __shared__ short As[2][64 * 32];    // 8 KB
    __shared__ short Bs[2][128 * 32];   // 16 KB
    const int K = 512;
    int tid = threadIdx.x;
    int wid = tid >> 6, lane = tid & 63;
    int quad = lane >> 4, l16 = lane & 15;
    int bM = blockIdx.x * 64, bN = blockIdx.y * 128;
    int wM = (wid >> 1) * 32, wN = (wid & 1) * 64;

    const short* Ag = (const short*)A;
    const short* Bg = (const short*)Bt;

    int rowS = tid >> 2, cg = tid & 3;   // 4 threads per row, 8 shorts each
    const short* gA = Ag + (size_t)(bM + rowS) * K + cg * 8;
    const short* gB0 = Bg + (size_t)(bN + rowS) * K + cg * 8;
    const short* gB1 = Bg + (size_t)(bN + 64 + rowS) * K + cg * 8;

    v4f acc[2][4] = {};
    for (int k0 = 0; k0 < K; k0 += 64) {
        #pragma unroll
        for (int s = 0; s < 2; s++) {
            load_lds16(gA + k0 + s * 32, As[s] + wid * 512);
            load_lds16(gB0 + k0 + s * 32, Bs[s] + wid * 512);
            load_lds16(gB1 + k0 + s * 32, Bs[s] + 2048 + wid * 512);
        }
        __syncthreads();
        #pragma unroll
        for (int s = 0; s < 2; s++) {
            v8s af[2], bf[4];
            #pragma unroll
            for (int i = 0; i < 2; i++)
                af[i] = *(const v8s*)(As[s] + (wM + i * 16 + l16) * 32 + quad * 8);
            #pragma unroll
            for (int j = 0; j < 4; j++)
                bf[j] = *(const v8s*)(Bs[s] + (wN + j * 16 + l16) * 32 + quad * 8);
            #pragma unroll
            for (int i = 0; i < 2; i++)
                #pragma unroll
                for (int j = 0; j < 4; j++)
                    acc[i][j] = __builtin_amdgcn_mfma_f32_16x16x32_bf16(af[i], bf[j], acc[i][j], 0, 0, 0);
        }
        __syncthreads();
    }

    #pragma unroll
    for (int i = 0; i < 2; i++) {
        int row = bM + wM + i * 16 + quad * 4;
        #pragma unroll
        for (int j = 0; j < 4; j++) {
            int col = bN + wN + j * 16 + l16;
            #pragma unroll
            for (int r = 0; r < 4; r++) {
                int rr = row + r;
                if (rr < M) {
                    float v = acc[i][j][r];
                    if (bias) v += bias[col];
                    if (res) v += res[(size_t)rr * N + col];
                    size_t idx = (size_t)rr * N + col;
                    if (C) C[idx] = v;
                    if (Cb) Cb[idx] = __float2bfloat16(v);
                }
            }
        }
    }
}

// ---------------- axial attention, flash-style MFMA ----------------
__global__ __launch_bounds__(256) void axial_flash(
    const unsigned short* __restrict__ qkvb, __hip_bfloat16* __restrict__ attn_b, int typ) {
    __shared__ short Ks[64 * 64];    // 8 KB, chunk-XOR swizzled
    __shared__ short Vs[64 * 64];    // 8 KB, linear
    __shared__ short Ps[64 * 72];    // 9 KB
    __shared__ float invl[64];

    int tid = threadIdx.x;
    int wid = tid >> 6, lane = tid & 63;
    int quad = lane >> 4, l16 = lane & 15;
    int n = blockIdx.x;
    int b = blockIdx.y >> 3, h = blockIdx.y & 7;
    size_t rowbase = (size_t)b * SEQ;
    int hoff = h * 64;

    #pragma unroll
    for (int it = 0; it < 2; it++) {
        int linear = it * 256 + tid;
        int slot = linear >> 3;
        int cd = linear & 7;
        int cs = cd ^ (slot & 7);
        int sp = (slot == 0) ? 0
               : (slot <= 48 ? (typ == 0 ? 1 + n * 48 + (slot - 1) : 1 + (slot - 1) * 48 + n) : 0);
        const unsigned short* srcK = qkvb + (rowbase + sp) * QKVN + hoff + 512 + cs * 8;
        load_lds16(srcK, Ks + it * 2048 + wid * 512 + lane * 8);
        const unsigned short* srcV = qkvb + (rowbase + sp) * QKVN + hoff + 1024 + cd * 8;
        load_lds16(srcV, Vs + it * 2048 + wid * 512 + lane * 8);
    }

    int qi = wid * 16 + l16;
    int sp_q = (qi >= 1 && qi <= 48)
             ? (typ == 0 ? 1 + n * 48 + (qi - 1) : 1 + (qi - 1) * 48 + n) : 0;
    const unsigned short* qptr = qkvb + (rowbase + sp_q) * QKVN + hoff + quad * 8;
    v8s qa0 = *(const v8s*)qptr;
    v8s qa1 = *(const v8s*)(qptr + 32);

    __syncthreads();

    if (n == 0 && tid < 64) {
        attn_b[rowbase * DIM + hoff + tid] =
            __float2bfloat16(bf2f(qkvb[rowbase * QKVN + hoff + 1024 + tid]));
    }

    v4f st[4];
    #pragma unroll
    for (int kt = 0; kt < 4; kt++) {
        int slot = kt * 16 + l16;
        int s7 = slot & 7;
        v8s blo = *(const v8s*)(Ks + slot * 64 + ((quad ^ s7) * 8));
        v8s bhi = *(const v8s*)(Ks + slot * 64 + (((4 + quad) ^ s7) * 8));
        v4f a = {};
        a = __builtin_amdgcn_mfma_f32_16x16x32_bf16(qa0, blo, a, 0, 0, 0);
        a = __builtin_amdgcn_mfma_f32_16x16x32_bf16(qa1, bhi, a, 0, 0, 0);
        st[kt] = a;
    }

    const float NEG = -3.0e38f;
    float sv[4][4];
    float pm[4] = {NEG, NEG, NEG, NEG};
    #pragma unroll
    for (int kt = 0; kt < 4; kt++) {
        int j = kt * 16 + l16;
        #pragma unroll
        for (int r = 0; r < 4; r++) {
            int i = wid * 16 + quad * 4 + r;
            bool ok = (i >= 1) && (i <= 48) && (j <= i);
            float v = ok ? st[kt][r] * 0.125f : NEG;
            sv[kt][r] = v;
            pm[r] = fmaxf(pm[r], v);
        }
    }
    #pragma unroll
    for (int r = 0; r < 4; r++)
        for (int o = 1; o < 16; o <<= 1) pm[r] = fmaxf(pm[r], __shfl_xor(pm[r], o));

    float ps[4] = {0.f, 0.f, 0.f, 0.f};
    #pragma unroll
    for (int kt = 0; kt < 4; kt++) {
        int j = kt * 16 + l16;
        #pragma unroll
        for (int r = 0; r < 4; r++) {
            float e = __expf(sv[kt][r] - pm[r]);
            ps[r] += e;
            Ps[(wid * 16 + quad * 4 + r) * 72 + j] = (short)__bfloat16_as_ushort(__float2bfloat16(e));
        }
    }
    #pragma unroll
    for (int r = 0; r < 4; r++)
        for (int o = 1; o < 16; o <<= 1) ps[r] += __shfl_xor(ps[r], o);
    if (l16 == 0) {
        #pragma unroll
        for (int r = 0; r < 4; r++)
            invl[wid * 16 + quad * 4 + r] = 1.0f / ps[r];
    }
    __syncthreads();

    #pragma unroll
    for (int qt = 0; qt < 4; qt++) {
        v4f oc = {};
        #pragma unroll
        for (int kc = 0; kc < 2; kc++) {
            v8s pa = *(const v8s*)(Ps + (qt * 16 + l16) * 72 + kc * 32 + quad * 8);
            v8s bfr;
            #pragma unroll
            for (int jj = 0; jj < 8; jj++)
                bfr[jj] = Vs[(kc * 32 + quad * 8 + jj) * 64 + wid * 16 + l16];
            oc = __builtin_amdgcn_mfma_f32_16x16x32_bf16(pa, bfr, oc, 0, 0, 0);
        }
        #pragma unroll
        for (int r = 0; r < 4; r++) {
            int i = qt * 16 + quad * 4 + r;
            if (i >= 1 && i <= 48) {
                int sp = typ == 0 ? 1 + n * 48 + (i - 1) : 1 + (i - 1) * 48 + n;
                attn_b[(rowbase + sp) * DIM + hoff + wid * 16 + l16] =
                    __float2bfloat16(oc[r] * invl[i]);
            }
        }
    }
}

// ---------------- nearby attention: flash-style MFMA tile kernel ----------------
// blocks 0..2303: attention tiles. blocks 2304..2319: special rows 0/2304 per (b,h).
__global__ __launch_bounds__(256) void nearby_flash(
    const unsigned short* __restrict__ qkvb, __hip_bfloat16* __restrict__ attn_b) {
    __shared__ short KV[256 * 64];          // 32 KB: K first, reused for V
    __shared__ __hip_bfloat16 Ps[16 * 264];
    __shared__ float redm[16 * 4];
    __shared__ float reds[16 * 4];

    int tid = threadIdx.x;
    int wid = tid >> 6, lane = tid & 63;
    int quad = lane >> 4, l16 = lane & 15;

    int idx = blockIdx.x;
    if (idx >= 2304) {      // special rows for one (b,h)
        int bh = idx - 2304;
        int b = bh >> 3, h = bh & 7;
        size_t rb = (size_t)b * SEQ;
        const unsigned short* vb = qkvb + rb * QKVN + h * 64 + 1024 + lane;
        float s0 = 0.f, s1 = 0.f, s2 = 0.f, s3 = 0.f;
        int j = wid;
        for (; j + 12 < SEQ; j += 16) {
            s0 += bf2f(vb[(size_t)j * QKVN]);
            s1 += bf2f(vb[(size_t)(j + 4) * QKVN]);
            s2 += bf2f(vb[(size_t)(j + 8) * QKVN]);
            s3 += bf2f(vb[(size_t)(j + 12) * QKVN]);
        }
        for (; j < SEQ; j += 4) s0 += bf2f(vb[(size_t)j * QKVN]);
        float* red = (float*)KV;
        red[wid * 64 + lane] = s0 + s1 + s2 + s3;
        __syncthreads();
        if (wid == 0) {
            float tot = red[lane] + red[64 + lane] + red[128 + lane] + red[192 + lane];
            attn_b[(rb + 2304) * DIM + h * 64 + lane] = __float2bfloat16(tot * (1.0f / 2305.0f));
            attn_b[rb * DIM + h * 64 + lane] = __float2bfloat16(bf2f(vb[0]));
        }
        return;
    }

    int bh = idx & 15;
    int tile = idx >> 4;
    int b = bh >> 3, h = bh & 7;
    int t = tile >> 4;
    int sxy = tile & 15;
    int hh0 = (sxy >> 2) * 4, ww0 = (sxy & 3) * 4;
    int nf = (t < 3 ? t : 3) + 1;
    int t0 = t - (nf - 1);

    size_t rowbase = (size_t)b * SEQ;
    int hoff = h * 64;

    #pragma unroll
    for (int it = 0; it < 8; it++) {
        int linear = it * 256 + tid;
        int slot = linear >> 3;
        int cd = linear & 7;
        int cs = cd ^ (slot & 7);
        int f = slot >> 6, uy = (slot >> 3) & 7, ux = slot & 7;
        int kh = hh0 - 2 + uy, kw = ww0 - 2 + ux;
        int kt = t0 + f;
        bool ok = (kh >= 0) && (kh < 16) && (kw >= 0) && (kw < 16) && (f < nf);
        int kp = ok ? (kt * 256 + kh * 16 + kw + 1) : 0;
        const unsigned short* src = qkvb + (rowbase + kp) * QKVN + hoff + 512 + cs * 8;
        load_lds16(src, KV + it * 2048 + wid * 512 + lane * 8);
    }

    int qp_f = t * 256 + (hh0 + (l16 >> 2)) * 16 + (ww0 + (l16 & 3));
    const unsigned short* qptr = qkvb + (rowbase + qp_f) * QKVN + hoff + quad * 8;
    v8s qa0 = *(const v8s*)qptr;
    v8s qa1 = *(const v8s*)(qptr + 32);

    __syncthreads();

    v4f st[4];
    #pragma unroll
    for (int k = 0; k < 4; k++) {
        int slot = (wid * 4 + k) * 16 + l16;
        int s7 = slot & 7;
        v8s blo = *(const v8s*)(KV + slot * 64 + ((quad ^ s7) * 8));
        v8s bhi = *(const v8s*)(KV + slot * 64 + (((4 + quad) ^ s7) * 8));
        v4f a = {};
        a = __builtin_amdgcn_mfma_f32_16x16x32_bf16(qa0, blo, a, 0, 0, 0);
        a = __builtin_amdgcn_mfma_f32_16x16x32_bf16(qa1, bhi, a, 0, 0, 0);
        st[k] = a;
    }

    const float NEG = -3.0e38f;
    float sv[4][4];
    float pm[4] = {NEG, NEG, NEG, NEG};
    #pragma unroll
    for (int k = 0; k < 4; k++) {
        int slot = (wid * 4 + k) * 16 + l16;
        int f = slot >> 6, uy = (slot >> 3) & 7, ux = slot & 7;
        int kh = hh0 - 2 + uy, kw = ww0 - 2 + ux;
        bool okb = (kh >= 0) && (kh < 16) && (kw >= 0) && (kw < 16) && (f < nf);
        int dyp2 = uy - quad;
        bool oky = okb && (dyp2 >= 0) && (dyp2 <= 4);
        #pragma unroll
        for (int r = 0; r < 4; r++) {
            int dxp2 = ux - r;
            bool ok = oky && (dxp2 >= 0) && (dxp2 <= 4);
            if (f == nf - 1) ok = ok && (dyp2 * 5 + dxp2 < 12);
            float v = ok ? st[k][r] * 0.125f : NEG;
            sv[k][r] = v;
            pm[r] = fmaxf(pm[r], v);
        }
    }
    #pragma unroll
    for (int r = 0; r < 4; r++)
        for (int o = 1; o < 16; o <<= 1) pm[r] = fmaxf(pm[r], __shfl_xor(pm[r], o));
    if (l16 == 0) {
        #pragma unroll
        for (int r = 0; r < 4; r++) redm[(quad * 4 + r) * 4 + wid] = pm[r];
    }
    __syncthreads();

    #pragma unroll
    for (int it = 0; it < 8; it++) {
        int linear = it * 256 + tid;
        int slot = linear >> 3;
        int cd = linear & 7;
        int f = slot >> 6, uy = (slot >> 3) & 7, ux = slot & 7;
        int kh = hh0 - 2 + uy, kw = ww0 - 2 + ux;
        int kt = t0 + f;
        bool ok = (kh >= 0) && (kh < 16) && (kw >= 0) && (kw < 16) && (f < nf);
        int kp = ok ? (kt * 256 + kh * 16 + kw + 1) : 0;
        const unsigned short* src = qkvb + (rowbase + kp) * QKVN + hoff + 1024 + cd * 8;
        load_lds16(src, KV + it * 2048 + wid * 512 + lane * 8);
    }

    float rm[4];
    #pragma unroll
    for (int r = 0; r < 4; r++) {
        int row = (quad * 4 + r) * 4;
        rm[r] = fmaxf(fmaxf(redm[row], redm[row + 1]), fmaxf(redm[row + 2], redm[row + 3]));
    }

    float ps[4] = {0.f, 0.f, 0.f, 0.f};
    #pragma unroll
    for (int k = 0; k < 4; k++) {
        int slot = (wid * 4 + k) * 16 + l16;
        #pragma unroll
        for (int r = 0; r < 4; r++) {
            float e = __expf(sv[k][r] - rm[r]);
            ps[r] += e;
            Ps[(quad * 4 + r) * 264 + slot] = __float2bfloat16(e);
        }
    }
    #pragma unroll
    for (int r = 0; r < 4; r++)
        for (int o = 1; o < 16; o <<= 1) ps[r] += __shfl_xor(ps[r], o);
    if (l16 == 0) {
        #pragma unroll
        for (int r = 0; r < 4; r++) reds[(quad * 4 + r) * 4 + wid] = ps[r];
    }
    __syncthreads();

    float inv[4];
    #pragma unroll
    for (int r = 0; r < 4; r++) {
        int row = (quad * 4 + r) * 4;
        float d = reds[row] + reds[row + 1] + reds[row + 2] + reds[row + 3];
        inv[r] = 1.0f / d;
    }

    v4f oc = {};
    #pragma unroll
    for (int kc = 0; kc < 8; kc++) {
        v8s pa = *(const v8s*)((const short*)Ps + l16 * 264 + kc * 32 + quad * 8);
        v8s bf;
        #pragma unroll
        for (int j = 0; j < 8; j++) {
            int slot = kc * 32 + quad * 8 + j;
            bf[j] = KV[slot * 64 + wid * 16 + l16];
        }
        oc = __builtin_amdgcn_mfma_f32_16x16x32_bf16(pa, bf, oc, 0, 0, 0);
    }

    #pragma unroll
    for (int r = 0; r < 4; r++) {
        int qp = t * 256 + (hh0 + quad) * 16 + (ww0 + r);
        if (qp != 0) {
            attn_b[(rowbase + qp) * DIM + hoff + wid * 16 + l16] =
                __float2bfloat16(oc[r] * inv[r]);
        }
    }
}

// ---------------- host launch ----------------
extern "C" void kernel_launch(void* const* d_in, const int* in_sizes, int n_in,
                              void* d_out, int out_size, void* d_ws, size_t ws_size,
                              hipStream_t stream) {
    const float* x = (const float*)d_in[0];
    float* xcur = (float*)d_out;

    char* ws = (char*)d_ws;
    size_t off = 0;
    auto alloc = [&](size_t bytes) -> void* {
        void* p = ws + off;
        off = (off + bytes + 255) & ~(size_t)255;
        return p;
    };
    __hip_bfloat16* wqkv  = (__hip_bfloat16*)alloc((size_t)3 * QKVN * DIM * 2);
    __hip_bfloat16* wo    = (__hip_bfloat16*)alloc((size_t)3 * DIM * DIM * 2);
    __hip_bfloat16* xb    = (__hip_bfloat16*)alloc((size_t)MPAD * DIM * 2);
    __hip_bfloat16* attnb = (__hip_bfloat16*)alloc((size_t)MPAD * DIM * 2);
    __hip_bfloat16* qkvb  = (__hip_bfloat16*)alloc((size_t)NROWS * QKVN * 2);

    const int nElem = NROWS * DIM;
    const int n4 = nElem / 4;

    WPack wp;
    for (int l = 0; l < 3; l++)
        for (int j = 0; j < 4; j++)
            wp.p[l * 4 + j] = (const float*)d_in[2 + l * 5 + j];
    prep_inputs<<<dim3(16, 16, 13), dim3(32, 8), 0, stream>>>(
        wp, wqkv, wo, (const float4*)x, (float4*)xcur, xb, n4);

    for (int l = 0; l < 3; l++) {
        gemm_lds<<<dim3(MPAD / 64, QKVN / 128), 256, 0, stream>>>(
            xb, wqkv + (size_t)l * QKVN * DIM, nullptr, nullptr, nullptr, qkvb, NROWS, QKVN);
        if (l < 2) {
            axial_flash<<<dim3(48, 16), 256, 0, stream>>>((const unsigned short*)qkvb, attnb, l);
        } else {
            nearby_flash<<<2304 + 16, 256, 0, stream>>>((const unsigned short*)qkvb, attnb);
        }
        const float* bo = (const float*)d_in[6 + l * 5];
        gemm_lds<<<dim3(MPAD / 64, DIM / 128), 256, 0, stream>>>(
            attnb, wo + (size_t)l * DIM * DIM, xcur, bo, xcur, xb, NROWS, DIM);
    }
}

// Round 12
// 290.615 us; speedup vs baseline: 3.0818x; 1.0159x over previous
//
#include <hip/hip_runtime.h>
#include <hip/hip_bf16.h>

#define SEQ 2305
#define NROWS 4610      // B*SEQ
#define MPAD 4736       // NROWS rounded up to 128
#define DIM 512
#define QKVN 1536

typedef __attribute__((ext_vector_type(8))) short v8s;
typedef __attribute__((ext_vector_type(4))) float v4f;

__device__ __forceinline__ float bf2f(unsigned short u) {
    return __uint_as_float(((unsigned)u) << 16);
}

__device__ __forceinline__ void load_lds16(const void* g, void* l) {
    __builtin_amdgcn_global_load_lds(
        (const __attribute__((address_space(1))) void*)g,
        (__attribute__((address_space(3))) void*)l, 16, 0, 0);
}

// ---------------- weight transpose + bf16 convert, fused with x copy/cast ----------------
struct WPack { const float* p[12]; };

__global__ void prep_inputs(WPack wp, __hip_bfloat16* __restrict__ wqkv,
                            __hip_bfloat16* __restrict__ wo,
                            const float4* __restrict__ xin, float4* __restrict__ xout,
                            __hip_bfloat16* __restrict__ xb, int n4) {
    int tx = threadIdx.x, ty = threadIdx.y;
    int m = blockIdx.z;
    if (m == 12) {   // copy x -> xcur (fp32) + xb (bf16), grid-stride
        int tidl = ty * 32 + tx;
        int bid = blockIdx.y * 16 + blockIdx.x;
        for (int i = bid * 256 + tidl; i < n4; i += 65536) {
            float4 v = xin[i];
            xout[i] = v;
            int j = i * 4;
            xb[j + 0] = __float2bfloat16(v.x);
            xb[j + 1] = __float2bfloat16(v.y);
            xb[j + 2] = __float2bfloat16(v.z);
            xb[j + 3] = __float2bfloat16(v.w);
        }
        return;
    }
    __shared__ float tile[32][33];
    const float* src = wp.p[m];
    int l = m >> 2, j = m & 3;
    __hip_bfloat16* dst = (j < 3) ? (wqkv + (size_t)l * QKVN * DIM + (size_t)j * DIM * DIM)
                                  : (wo + (size_t)l * DIM * DIM);
    int bx = blockIdx.x * 32, by = blockIdx.y * 32;
    #pragma unroll
    for (int i = 0; i < 4; i++)
        tile[ty + 8 * i][tx] = src[(size_t)(by + ty + 8 * i) * DIM + bx + tx];
    __syncthreads();
    #pragma unroll
    for (int i = 0; i < 4; i++)
        dst[(size_t)(bx + ty + 8 * i) * DIM + by + tx] = __float2bfloat16(tile[tx][ty + 8 * i]);
}

// ---------------- LDS-staged bf16 GEMM, 64x128 tile, BK=64 (twin 32-k sub-buffers) ----------------
__global__ __launch_bounds__(256) void gemm_lds(
    const __hip_bfloat16* __restrict__ A, const __hip_bfloat16* __restrict__ Bt,
    float* __restrict__ C, const float* __restrict__ bias, const float* __restrict__ res,
    __hip_bfloat16* __restrict__ Cb, int M, int N) {
    __shared__ short As[2][64 * 32];    // 8 KB
    __shared__ short Bs[2][128 * 32];   // 16 KB
    const int K = 512;
    int tid = threadIdx.x;
    int wid = tid >> 6, lane = tid & 63;
    int quad = lane >> 4, l16 = lane & 15;
    int bM = blockIdx.x * 64, bN = blockIdx.y * 128;
    int wM = (wid >> 1) * 32, wN = (wid & 1) * 64;

    const short* Ag = (const short*)A;
    const short* Bg = (const short*)Bt;

    int rowS = tid >> 2, cg = tid & 3;
    const short* gA = Ag + (size_t)(bM + rowS) * K + cg * 8;
    const short* gB0 = Bg + (size_t)(bN + rowS) * K + cg * 8;
    const short* gB1 = Bg + (size_t)(bN + 64 + rowS) * K + cg * 8;

    v4f acc[2][4] = {};
    for (int k0 = 0; k0 < K; k0 += 64) {
        #pragma unroll
        for (int s = 0; s < 2; s++) {
            load_lds16(gA + k0 + s * 32, As[s] + wid * 512);
            load_lds16(gB0 + k0 + s * 32, Bs[s] + wid * 512);
            load_lds16(gB1 + k0 + s * 32, Bs[s] + 2048 + wid * 512);
        }
        __syncthreads();
        #pragma unroll
        for (int s = 0; s < 2; s++) {
            v8s af[2], bf[4];
            #pragma unroll
            for (int i = 0; i < 2; i++)
                af[i] = *(const v8s*)(As[s] + (wM + i * 16 + l16) * 32 + quad * 8);
            #pragma unroll
            for (int j = 0; j < 4; j++)
                bf[j] = *(const v8s*)(Bs[s] + (wN + j * 16 + l16) * 32 + quad * 8);
            #pragma unroll
            for (int i = 0; i < 2; i++)
                #pragma unroll
                for (int j = 0; j < 4; j++)
                    acc[i][j] = __builtin_amdgcn_mfma_f32_16x16x32_bf16(af[i], bf[j], acc[i][j], 0, 0, 0);
        }
        __syncthreads();
    }

    #pragma unroll
    for (int i = 0; i < 2; i++) {
        int row = bM + wM + i * 16 + quad * 4;
        #pragma unroll
        for (int j = 0; j < 4; j++) {
            int col = bN + wN + j * 16 + l16;
            #pragma unroll
            for (int r = 0; r < 4; r++) {
                int rr = row + r;
                if (rr < M) {
                    float v = acc[i][j][r];
                    if (bias) v += bias[col];
                    if (res) v += res[(size_t)rr * N + col];
                    size_t idx = (size_t)rr * N + col;
                    if (C) C[idx] = v;
                    if (Cb) Cb[idx] = __float2bfloat16(v);
                }
            }
        }
    }
}

// ---------------- axial attention, flash-style MFMA ----------------
__global__ __launch_bounds__(256) void axial_flash(
    const unsigned short* __restrict__ qkvb, __hip_bfloat16* __restrict__ attn_b, int typ) {
    __shared__ short Ks[64 * 64];    // 8 KB, chunk-XOR swizzled
    __shared__ short Vs[64 * 64];    // 8 KB, linear
    __shared__ short Ps[64 * 72];    // 9 KB
    __shared__ float invl[64];

    int tid = threadIdx.x;
    int wid = tid >> 6, lane = tid & 63;
    int quad = lane >> 4, l16 = lane & 15;
    int n = blockIdx.x;
    int b = blockIdx.y >> 3, h = blockIdx.y & 7;
    size_t rowbase = (size_t)b * SEQ;
    int hoff = h * 64;

    #pragma unroll
    for (int it = 0; it < 2; it++) {
        int linear = it * 256 + tid;
        int slot = linear >> 3;
        int cd = linear & 7;
        int cs = cd ^ (slot & 7);
        int sp = (slot == 0) ? 0
               : (slot <= 48 ? (typ == 0 ? 1 + n * 48 + (slot - 1) : 1 + (slot - 1) * 48 + n) : 0);
        const unsigned short* srcK = qkvb + (rowbase + sp) * QKVN + hoff + 512 + cs * 8;
        load_lds16(srcK, Ks + it * 2048 + wid * 512 + lane * 8);
        const unsigned short* srcV = qkvb + (rowbase + sp) * QKVN + hoff + 1024 + cd * 8;
        load_lds16(srcV, Vs + it * 2048 + wid * 512 + lane * 8);
    }

    int qi = wid * 16 + l16;
    int sp_q = (qi >= 1 && qi <= 48)
             ? (typ == 0 ? 1 + n * 48 + (qi - 1) : 1 + (qi - 1) * 48 + n) : 0;
    const unsigned short* qptr = qkvb + (rowbase + sp_q) * QKVN + hoff + quad * 8;
    v8s qa0 = *(const v8s*)qptr;
    v8s qa1 = *(const v8s*)(qptr + 32);

    __syncthreads();

    if (n == 0 && tid < 64) {
        attn_b[rowbase * DIM + hoff + tid] =
            __float2bfloat16(bf2f(qkvb[rowbase * QKVN + hoff + 1024 + tid]));
    }

    v4f st[4];
    #pragma unroll
    for (int kt = 0; kt < 4; kt++) {
        int slot = kt * 16 + l16;
        int s7 = slot & 7;
        v8s blo = *(const v8s*)(Ks + slot * 64 + ((quad ^ s7) * 8));
        v8s bhi = *(const v8s*)(Ks + slot * 64 + (((4 + quad) ^ s7) * 8));
        v4f a = {};
        a = __builtin_amdgcn_mfma_f32_16x16x32_bf16(qa0, blo, a, 0, 0, 0);
        a = __builtin_amdgcn_mfma_f32_16x16x32_bf16(qa1, bhi, a, 0, 0, 0);
        st[kt] = a;
    }

    const float NEG = -3.0e38f;
    float sv[4][4];
    float pm[4] = {NEG, NEG, NEG, NEG};
    #pragma unroll
    for (int kt = 0; kt < 4; kt++) {
        int j = kt * 16 + l16;
        #pragma unroll
        for (int r = 0; r < 4; r++) {
            int i = wid * 16 + quad * 4 + r;
            bool ok = (i >= 1) && (i <= 48) && (j <= i);
            float v = ok ? st[kt][r] * 0.125f : NEG;
            sv[kt][r] = v;
            pm[r] = fmaxf(pm[r], v);
        }
    }
    #pragma unroll
    for (int r = 0; r < 4; r++)
        for (int o = 1; o < 16; o <<= 1) pm[r] = fmaxf(pm[r], __shfl_xor(pm[r], o));

    float ps[4] = {0.f, 0.f, 0.f, 0.f};
    #pragma unroll
    for (int kt = 0; kt < 4; kt++) {
        int j = kt * 16 + l16;
        #pragma unroll
        for (int r = 0; r < 4; r++) {
            float e = __expf(sv[kt][r] - pm[r]);
            ps[r] += e;
            Ps[(wid * 16 + quad * 4 + r) * 72 + j] = (short)__bfloat16_as_ushort(__float2bfloat16(e));
        }
    }
    #pragma unroll
    for (int r = 0; r < 4; r++)
        for (int o = 1; o < 16; o <<= 1) ps[r] += __shfl_xor(ps[r], o);
    if (l16 == 0) {
        #pragma unroll
        for (int r = 0; r < 4; r++)
            invl[wid * 16 + quad * 4 + r] = 1.0f / ps[r];
    }
    __syncthreads();

    #pragma unroll
    for (int qt = 0; qt < 4; qt++) {
        v4f oc = {};
        #pragma unroll
        for (int kc = 0; kc < 2; kc++) {
            v8s pa = *(const v8s*)(Ps + (qt * 16 + l16) * 72 + kc * 32 + quad * 8);
            v8s bfr;
            #pragma unroll
            for (int jj = 0; jj < 8; jj++)
                bfr[jj] = Vs[(kc * 32 + quad * 8 + jj) * 64 + wid * 16 + l16];
            oc = __builtin_amdgcn_mfma_f32_16x16x32_bf16(pa, bfr, oc, 0, 0, 0);
        }
        #pragma unroll
        for (int r = 0; r < 4; r++) {
            int i = qt * 16 + quad * 4 + r;
            if (i >= 1 && i <= 48) {
                int sp = typ == 0 ? 1 + n * 48 + (i - 1) : 1 + (i - 1) * 48 + n;
                attn_b[(rowbase + sp) * DIM + hoff + wid * 16 + l16] =
                    __float2bfloat16(oc[r] * invl[i]);
            }
        }
    }
}

// ---------------- mean of all V rows + special seq rows 0 / 2304 ----------------
__global__ void meanv_part(const unsigned short* __restrict__ qkvb, float* __restrict__ part) {
    int b = blockIdx.x >> 4, ch = blockIdx.x & 15;
    int col = blockIdx.y * 256 + threadIdx.x;
    int j0 = ch * 145, j1 = j0 + 145;
    if (j1 > SEQ) j1 = SEQ;
    const unsigned short* p = qkvb + (size_t)b * SEQ * QKVN + 1024 + col;
    float s = 0.f;
    #pragma unroll 4
    for (int j = j0; j < j1; j++) s += bf2f(p[(size_t)j * QKVN]);
    part[((size_t)(b * 16 + ch)) * 512 + col] = s;
}
__global__ void meanv_fold(const float* __restrict__ part,
                           const unsigned short* __restrict__ qkvb,
                           __hip_bfloat16* __restrict__ attn_b) {
    int b = blockIdx.x;
    int col = blockIdx.y * 256 + threadIdx.x;
    float s = 0.f;
    #pragma unroll
    for (int ch = 0; ch < 16; ch++) s += part[((size_t)(b * 16 + ch)) * 512 + col];
    attn_b[((size_t)b * SEQ + 2304) * DIM + col] = __float2bfloat16(s * (1.0f / 2305.0f));
    attn_b[((size_t)b * SEQ) * DIM + col] =
        __float2bfloat16(bf2f(qkvb[(size_t)b * SEQ * QKVN + 1024 + col]));
}

// ---------------- nearby attention v2: K direct-global gather, V in LDS halves ----------------
// One block = 16 queries (4x4 tile) x one (b,h). Grid 2304. 256 thr = 4 waves.
__global__ __launch_bounds__(256) void nearby_flash(
    const unsigned short* __restrict__ qkvb, __hip_bfloat16* __restrict__ attn_b) {
    __shared__ short Vs[128 * 64];          // 16 KB, one V half (chunk-XOR key=(slot>>3)&7)
    __shared__ __hip_bfloat16 Ps[16 * 264]; // 8.25 KB
    __shared__ float redm[16 * 4];
    __shared__ float reds[16 * 4];

    int tid = threadIdx.x;
    int wid = tid >> 6, lane = tid & 63;
    int quad = lane >> 4, l16 = lane & 15;

    int idx = blockIdx.x;
    int bh = idx & 15;
    int tile = idx >> 4;
    int b = bh >> 3, h = bh & 7;
    int t = tile >> 4;
    int sxy = tile & 15;
    int hh0 = (sxy >> 2) * 4, ww0 = (sxy & 3) * 4;
    int nf = (t < 3 ? t : 3) + 1;
    int t0 = t - (nf - 1);
    size_t rowbase = (size_t)b * SEQ;
    int hoff = h * 64;

    auto slot_kp = [&](int slot) -> int {
        int f = slot >> 6, uy = (slot >> 3) & 7, ux = slot & 7;
        int kh = hh0 - 2 + uy, kw = ww0 - 2 + ux;
        int kt = t0 + f;
        bool ok = (kh >= 0) && (kh < 16) && (kw >= 0) && (kw < 16) && (f < nf);
        return ok ? (kt * 256 + kh * 16 + kw + 1) : 0;
    };

    // Q A-frags
    int qp_f = t * 256 + (hh0 + (l16 >> 2)) * 16 + (ww0 + (l16 & 3));
    const unsigned short* qptr = qkvb + (rowbase + qp_f) * QKVN + hoff + quad * 8;
    v8s qa0 = *(const v8s*)qptr;
    v8s qa1 = *(const v8s*)(qptr + 32);

    // K B-frags direct from global (wave wid owns slots [wid*64, wid*64+64))
    v8s kb_lo[4], kb_hi[4];
    #pragma unroll
    for (int k = 0; k < 4; k++) {
        int slot = (wid * 4 + k) * 16 + l16;
        int kp = slot_kp(slot);
        const unsigned short* kr = qkvb + (rowbase + kp) * QKVN + hoff + 512;
        kb_lo[k] = *(const v8s*)(kr + quad * 8);
        kb_hi[k] = *(const v8s*)(kr + 32 + quad * 8);
    }

    // issue V half-0 staging (slots 0..127)
    #pragma unroll
    for (int it = 0; it < 4; it++) {
        int linear = it * 256 + tid;
        int slot = linear >> 3;
        int cd = linear & 7;
        int cs = cd ^ ((slot >> 3) & 7);
        int kp = slot_kp(slot);
        const unsigned short* src = qkvb + (rowbase + kp) * QKVN + hoff + 1024 + cs * 8;
        load_lds16(src, Vs + it * 2048 + wid * 512 + lane * 8);
    }

    // ---- S = Q K^T ----
    v4f st[4];
    #pragma unroll
    for (int k = 0; k < 4; k++) {
        v4f a = {};
        a = __builtin_amdgcn_mfma_f32_16x16x32_bf16(qa0, kb_lo[k], a, 0, 0, 0);
        a = __builtin_amdgcn_mfma_f32_16x16x32_bf16(qa1, kb_hi[k], a, 0, 0, 0);
        st[k] = a;
    }

    // ---- scale + geometric mask + row-max partials ----
    const float NEG = -3.0e38f;
    float sv[4][4];
    float pm[4] = {NEG, NEG, NEG, NEG};
    #pragma unroll
    for (int k = 0; k < 4; k++) {
        int slot = (wid * 4 + k) * 16 + l16;
        int f = slot >> 6, uy = (slot >> 3) & 7, ux = slot & 7;
        int kh = hh0 - 2 + uy, kw = ww0 - 2 + ux;
        bool okb = (kh >= 0) && (kh < 16) && (kw >= 0) && (kw < 16) && (f < nf);
        int dyp2 = uy - quad;
        bool oky = okb && (dyp2 >= 0) && (dyp2 <= 4);
        #pragma unroll
        for (int r = 0; r < 4; r++) {
            int dxp2 = ux - r;
            bool ok = oky && (dxp2 >= 0) && (dxp2 <= 4);
            if (f == nf - 1) ok = ok && (dyp2 * 5 + dxp2 < 12);
            float v = ok ? st[k][r] * 0.125f : NEG;
            sv[k][r] = v;
            pm[r] = fmaxf(pm[r], v);
        }
    }
    #pragma unroll
    for (int r = 0; r < 4; r++)
        for (int o = 1; o < 16; o <<= 1) pm[r] = fmaxf(pm[r], __shfl_xor(pm[r], o));
    if (l16 == 0) {
        #pragma unroll
        for (int r = 0; r < 4; r++) redm[(quad * 4 + r) * 4 + wid] = pm[r];
    }
    __syncthreads();   // barrier 1: redm visible, V half-0 staged

    float rm[4];
    #pragma unroll
    for (int r = 0; r < 4; r++) {
        int row = (quad * 4 + r) * 4;
        rm[r] = fmaxf(fmaxf(redm[row], redm[row + 1]), fmaxf(redm[row + 2], redm[row + 3]));
    }

    float ps[4] = {0.f, 0.f, 0.f, 0.f};
    #pragma unroll
    for (int k = 0; k < 4; k++) {
        int slot = (wid * 4 + k) * 16 + l16;
        #pragma unroll
        for (int r = 0; r < 4; r++) {
            float e = __expf(sv[k][r] - rm[r]);
            ps[r] += e;
            Ps[(quad * 4 + r) * 264 + slot] = __float2bfloat16(e);
        }
    }
    #pragma unroll
    for (int r = 0; r < 4; r++)
        for (int o = 1; o < 16; o <<= 1) ps[r] += __shfl_xor(ps[r], o);
    if (l16 == 0) {
        #pragma unroll
        for (int r = 0; r < 4; r++) reds[(quad * 4 + r) * 4 + wid] = ps[r];
    }
    __syncthreads();   // barrier 2: Ps + reds visible

    float inv[4];
    #pragma unroll
    for (int r = 0; r < 4; r++) {
        int row = (quad * 4 + r) * 4;
        float d = reds[row] + reds[row + 1] + reds[row + 2] + reds[row + 3];
        inv[r] = 1.0f / d;
    }

    // ---- PV half 0 (slots 0..127): wave wid owns dims [wid*16, wid*16+16) ----
    int dcol = wid * 16 + l16;
    int c_r = dcol >> 3, d7 = dcol & 7;
    v4f oc = {};
    #pragma unroll
    for (int kc = 0; kc < 4; kc++) {
        v8s pa = *(const v8s*)((const short*)Ps + l16 * 264 + kc * 32 + quad * 8);
        v8s bf;
        #pragma unroll
        for (int j = 0; j < 8; j++) {
            int slot = kc * 32 + quad * 8 + j;
            int key = (slot >> 3) & 7;
            bf[j] = Vs[(slot & 127) * 64 + ((c_r ^ key) * 8) + d7];
        }
        oc = __builtin_amdgcn_mfma_f32_16x16x32_bf16(pa, bf, oc, 0, 0, 0);
    }
    __syncthreads();   // barrier 3: half-0 reads done

    // stage V half-1 (slots 128..255)
    #pragma unroll
    for (int it = 0; it < 4; it++) {
        int linear = 1024 + it * 256 + tid;
        int slot = linear >> 3;
        int cd = linear & 7;
        int cs = cd ^ ((slot >> 3) & 7);
        int kp = slot_kp(slot);
        const unsigned short* src = qkvb + (rowbase + kp) * QKVN + hoff + 1024 + cs * 8;
        load_lds16(src, Vs + it * 2048 + wid * 512 + lane * 8);
    }
    __syncthreads();   // barrier 4: half-1 staged

    #pragma unroll
    for (int kc = 4; kc < 8; kc++) {
        v8s pa = *(const v8s*)((const short*)Ps + l16 * 264 + kc * 32 + quad * 8);
        v8s bf;
        #pragma unroll
        for (int j = 0; j < 8; j++) {
            int slot = kc * 32 + quad * 8 + j;
            int key = (slot >> 3) & 7;
            bf[j] = Vs[(slot & 127) * 64 + ((c_r ^ key) * 8) + d7];
        }
        oc = __builtin_amdgcn_mfma_f32_16x16x32_bf16(pa, bf, oc, 0, 0, 0);
    }

    // ---- write O ----
    #pragma unroll
    for (int r = 0; r < 4; r++) {
        int qp = t * 256 + (hh0 + quad) * 16 + (ww0 + r);
        if (qp != 0) {
            attn_b[(rowbase + qp) * DIM + hoff + dcol] =
                __float2bfloat16(oc[r] * inv[r]);
        }
    }
}

// ---------------- host launch ----------------
extern "C" void kernel_launch(void* const* d_in, const int* in_sizes, int n_in,
                              void* d_out, int out_size, void* d_ws, size_t ws_size,
                              hipStream_t stream) {
    const float* x = (const float*)d_in[0];
    float* xcur = (float*)d_out;

    char* ws = (char*)d_ws;
    size_t off = 0;
    auto alloc = [&](size_t bytes) -> void* {
        void* p = ws + off;
        off = (off + bytes + 255) & ~(size_t)255;
        return p;
    };
    __hip_bfloat16* wqkv  = (__hip_bfloat16*)alloc((size_t)3 * QKVN * DIM * 2);
    __hip_bfloat16* wo    = (__hip_bfloat16*)alloc((size_t)3 * DIM * DIM * 2);
    __hip_bfloat16* xb    = (__hip_bfloat16*)alloc((size_t)MPAD * DIM * 2);
    __hip_bfloat16* attnb = (__hip_bfloat16*)alloc((size_t)MPAD * DIM * 2);
    float* part           = (float*)alloc((size_t)2 * 16 * 512 * 4);
    __hip_bfloat16* qkvb  = (__hip_bfloat16*)alloc((size_t)NROWS * QKVN * 2);

    const int nElem = NROWS * DIM;
    const int n4 = nElem / 4;

    WPack wp;
    for (int l = 0; l < 3; l++)
        for (int j = 0; j < 4; j++)
            wp.p[l * 4 + j] = (const float*)d_in[2 + l * 5 + j];
    prep_inputs<<<dim3(16, 16, 13), dim3(32, 8), 0, stream>>>(
        wp, wqkv, wo, (const float4*)x, (float4*)xcur, xb, n4);

    for (int l = 0; l < 3; l++) {
        gemm_lds<<<dim3(MPAD / 64, QKVN / 128), 256, 0, stream>>>(
            xb, wqkv + (size_t)l * QKVN * DIM, nullptr, nullptr, nullptr, qkvb, NROWS, QKVN);
        if (l < 2) {
            axial_flash<<<dim3(48, 16), 256, 0, stream>>>((const unsigned short*)qkvb, attnb, l);
        } else {
            meanv_part<<<dim3(32, 2), 256, 0, stream>>>((const unsigned short*)qkvb, part);
            meanv_fold<<<dim3(2, 2), 256, 0, stream>>>(part, (const unsigned short*)qkvb, attnb);
            nearby_flash<<<2304, 256, 0, stream>>>((const unsigned short*)qkvb, attnb);
        }
        const float* bo = (const float*)d_in[6 + l * 5];
        gemm_lds<<<dim3(MPAD / 64, DIM / 128), 256, 0, stream>>>(
            attnb, wo + (size_t)l * DIM * DIM, xcur, bo, xcur, xb, NROWS, DIM);
    }
}